// Round 8
// baseline (2240.195 us; speedup 1.0000x reference)
//
#include <hip/hip_runtime.h>

#define TT 200
#define XD 65
#define ROWSTR (TT * XD)  // 13000

typedef _Float16 h2 __attribute__((ext_vector_type(2)));
typedef _Float16 half8 __attribute__((ext_vector_type(8)));
typedef float f32x4 __attribute__((ext_vector_type(4)));

#define MFMA16 __builtin_amdgcn_mfma_f32_16x16x32_f16

// ---- ws dword offsets: prepacked f16 B-fragment pools + feat frags ----
#define GOFF_WXC 0
#define GOFF_WXV 8192
#define GOFF_WHC 16384
#define GOFF_WHV 24576
#define GOFF_SCC 32768
#define GOFF_SCV 34816
#define GOFF_SVV 36864
#define GOFF_SVC 38912
#define GOFF_PC0 40960
#define GOFF_PV0 43008
#define GOFF_PC1 45056
#define GOFF_PV1 46080
#define GTOT     47104
#define WS_X     47104  // feat frags: 256 blocks * 200 t * 512 dw

// ---- LDS dword offsets (tiles only) ----
#define L_HC0 0      // 512-dw tiles: [16 rows][64 f16] swizzled (rows 8-15 stay 0)
#define L_HC1 512
#define L_HV0 1024
#define L_HV1 1536
#define L_Y0C0 2048
#define L_Y0C1 2560
#define L_Y0V  3072
#define L_CK   3584  // 2 x 8 floats (click double buffer)
#define L_PART 3600  // 32 floats
#define L_TOT  3632  // 14,528 B

__device__ __forceinline__ unsigned pk(float lo, float hi) {
  union { h2 h; unsigned u; } c;
  c.h.x = (_Float16)lo;
  c.h.y = (_Float16)hi;
  return c.u;
}

__device__ __forceinline__ float fexp2(float x) {
#if __has_builtin(__builtin_amdgcn_exp2f)
  return __builtin_amdgcn_exp2f(x);
#else
  return __expf(x * 0.6931471805599453f);
#endif
}
__device__ __forceinline__ float frcp(float x) {
#if __has_builtin(__builtin_amdgcn_rcpf)
  return __builtin_amdgcn_rcpf(x);
#else
  return 1.0f / x;
#endif
}
__device__ __forceinline__ float sigm(float x) { return frcp(1.f + fexp2(x * -1.44269504f)); }
__device__ __forceinline__ float tanh_fast(float x) {
  return fmaf(2.f, frcp(1.f + fexp2(x * -2.88539008f)), -1.f);
}
__device__ __forceinline__ float leaky(float x) { return x > 0.0f ? x : 0.3f * x; }
__device__ __forceinline__ f32x4 sp4(float v) { f32x4 r = {v, v, v, v}; return r; }

__device__ __forceinline__ int swz(int b) { return b ^ ((b >> 3) & 0x70); }

// A-frag: row = lane&15, k = kh*32 + 8*(lane>>4) + i
__device__ __forceinline__ half8 lda(const char* smc, int dwoff, int kh, int lane) {
  int byte = (lane & 15) * 128 + kh * 64 + ((lane >> 4) << 4);
  union { uint4 u; half8 h; } c;
  c.u = *(const uint4*)(smc + (dwoff << 2) + swz(byte));
  return c.h;
}
// B-frag from global ws pool
__device__ __forceinline__ half8 ldg8(const unsigned* ws, int off, int n, int kh, int lane) {
  union { uint4 u; half8 h; } c;
  c.u = *(const uint4*)(ws + off + (((n * 2 + kh) * 64 + lane) << 2));
  return c.h;
}

// ---- prepack: f32 weights -> f16 B-fragment pools in ws ----
extern "C" __global__ void prepack(const float* __restrict__ Wxc, const float* __restrict__ Wxv,
                                   const float* __restrict__ Whc, const float* __restrict__ Whv,
                                   const float* __restrict__ Wscc, const float* __restrict__ Wscv,
                                   const float* __restrict__ Wsvv, const float* __restrict__ Wsvc,
                                   const float* __restrict__ Wpc0, const float* __restrict__ Wpv0,
                                   const float* __restrict__ Wpc1, const float* __restrict__ Wpv1,
                                   unsigned* __restrict__ wsout) {
  int idx = blockIdx.x * 256 + threadIdx.x;
  if (idx >= GTOT) return;
  const float* W; int base, ncol;
  if      (idx < GOFF_WXV) { W = Wxc;  base = GOFF_WXC; ncol = 256; }
  else if (idx < GOFF_WHC) { W = Wxv;  base = GOFF_WXV; ncol = 256; }
  else if (idx < GOFF_WHV) { W = Whc;  base = GOFF_WHC; ncol = 256; }
  else if (idx < GOFF_SCC) { W = Whv;  base = GOFF_WHV; ncol = 256; }
  else if (idx < GOFF_SCV) { W = Wscc; base = GOFF_SCC; ncol = 64; }
  else if (idx < GOFF_SVV) { W = Wscv; base = GOFF_SCV; ncol = 64; }
  else if (idx < GOFF_SVC) { W = Wsvv; base = GOFF_SVV; ncol = 64; }
  else if (idx < GOFF_PC0) { W = Wsvc; base = GOFF_SVC; ncol = 64; }
  else if (idx < GOFF_PV0) { W = Wpc0; base = GOFF_PC0; ncol = 64; }
  else if (idx < GOFF_PC1) { W = Wpv0; base = GOFF_PV0; ncol = 64; }
  else if (idx < GOFF_PV1) { W = Wpc1; base = GOFF_PC1; ncol = 32; }
  else                     { W = Wpv1; base = GOFF_PV1; ncol = 32; }
  int local = idx - base;
  int d = local & 3, lane = (local >> 2) & 63, nk = local >> 8;
  int kh = nk & 1, n = nk >> 1;
  int k0 = kh * 32 + ((lane >> 4) << 3) + (d << 1);
  int c = n * 16 + (lane & 15);
  wsout[idx] = pk(W[k0 * ncol + c], W[(k0 + 1) * ncol + c]);
}

// ---- xpack: feats -> f16 A-frag stream [block][t][lane][8dw] ----
extern "C" __global__ void xpack(const float* __restrict__ x, unsigned* __restrict__ wsx) {
  int bt = blockIdx.x;             // 256*200
  int b = bt / 200, t = bt - b * 200;
  int tid = threadIdx.x;           // 512
  int lane = tid >> 3, d = tid & 7;
  int row = b * 8 + (lane & 7);
  int k = ((d & 4) ? 32 : 0) + ((lane >> 4) << 3) + ((d & 3) << 1);
  const float* p = x + (size_t)row * ROWSTR + t * XD + k;
  wsx[(size_t)bt * 512 + tid] = pk(p[0], p[1]);
}

// ---- per-q elementwise sub-macros (literal Q only; see rule on dyn indexing) ----
#define CGELEM(Q, HNEW)                                                                     \
  {                                                                                         \
    bool gp = (&gp4.x)[Q] >= 0.5f;                                                          \
    float f = sigm(a0_[Q]), ii = sigm(a1_[Q]), o = sigm(a2_[Q]);                            \
    float gc = tanh_fast(a3_[Q]);                                                           \
    float sh = tanh_fast(gp ? pscv[Q] : pscc[Q]);                                           \
    float s = sh + ii * gc + (gp ? 0.f : f * st[Q]);                                        \
    st[Q] = s;                                                                              \
    float hcn = o * tanh_fast(s);                                                           \
    *(_Float16*)(smc + ((HNEW) << 2) + swz((l4 * 4 + Q) * 128 + col2)) = (_Float16)hcn;     \
  }
#define VGELEM(Q)                                                                           \
  {                                                                                         \
    fvv[Q] = sigm(a0_[Q]); ivv[Q] = sigm(a1_[Q]); ovv[Q] = sigm(a2_[Q]);                    \
    gvv[Q] = tanh_fast(a3_[Q]); psv[Q] = psvv[Q];                                           \
  }
#define Y0VW(Q)                                                                             \
  *(_Float16*)(smc + (L_Y0V << 2) + swz((l4 * 4 + Q) * 128 + col2)) = (_Float16)leaky(apv[Q]);
#define VSELEM(Q, HVNEW)                                                                    \
  {                                                                                         \
    bool g = (&g4.x)[Q] >= 0.5f;                                                            \
    float sh = tanh_fast(g ? psv[Q] + psvc[Q] : psv[Q]);                                    \
    float s = sh + (g ? fvv[Q] * st[Q] + ivv[Q] * gvv[Q] : st[Q]);                          \
    st[Q] = s;                                                                              \
    float hvn = g ? ovv[Q] * tanh_fast(s) : hvold[Q];                                       \
    hvold[Q] = hvn;                                                                         \
    *(_Float16*)(smc + ((HVNEW) << 2) + swz((l4 * 4 + Q) * 128 + col2)) = (_Float16)hvn;    \
  }
#define Y0CW(Q, Y0W)                                                                        \
  *(_Float16*)(smc + ((Y0W) << 2) + swz((l4 * 4 + Q) * 128 + col2)) = (_Float16)leaky(ap[Q]);
#define HEADQ(Q)                                                                            \
  {                                                                                         \
    float tq = leaky(ah[Q]) * wfh;                                                          \
    tq += __shfl_xor(tq, 1, 64);                                                            \
    tq += __shfl_xor(tq, 2, 64);                                                            \
    tq += __shfl_xor(tq, 4, 64);                                                            \
    tq += __shfl_xor(tq, 8, 64);                                                            \
    if (l15 == 0 && l4 < 2)                                                                 \
      smf[L_PART + ((w8 < 2) ? 0 : 16) + (w8 & 1) * 8 + (l4 * 4 + Q)] = tq;                 \
  }

// One RNN step; parity constants compile-time via 2x-unrolled caller.
#define STEP(T, HCUR, HNEW, HVCUR, HVNEW, Y0W, Y0P, CKP, CKC, FC0, FC1, FN0, FN1)             \
  {                                                                                           \
    if ((T) >= 2 && wid == 7 && lane < 8) {                                                   \
      float pc = sigm(smf[L_PART + lane] + smf[L_PART + 8 + lane] + bfc);                     \
      float pv = sigm(smf[L_PART + 16 + lane] + smf[L_PART + 24 + lane] + bfv);               \
      o2[(size_t)(r0 + lane) * TT + ((T) - 2)] = make_float2(pc, pv * pc);                    \
    }                                                                                         \
    half8 hv0 = lda(smc, HVCUR, 0, lane), hv1 = lda(smc, HVCUR, 1, lane);                     \
    if (cw) {                                                                                 \
      half8 hc0 = lda(smc, HCUR, 0, lane), hc1 = lda(smc, HCUR, 1, lane);                     \
      f32x4 a0_ = sp4(bgate[0]), a1_ = sp4(bgate[1]), a2_ = sp4(bgate[2]),                    \
            a3_ = sp4(bgate[3]);                                                              \
      __builtin_amdgcn_s_setprio(1);                                                          \
      a0_ = MFMA16(FC0, wxF[0], a0_, 0, 0, 0);                                                \
      a0_ = MFMA16(FC1, wxF[1], a0_, 0, 0, 0);                                                \
      a0_ = MFMA16(hc0, whF[0], a0_, 0, 0, 0);                                                \
      a0_ = MFMA16(hc1, whF[1], a0_, 0, 0, 0);                                                \
      a1_ = MFMA16(FC0, wxF[2], a1_, 0, 0, 0);                                                \
      a1_ = MFMA16(FC1, wxF[3], a1_, 0, 0, 0);                                                \
      a1_ = MFMA16(hc0, whF[2], a1_, 0, 0, 0);                                                \
      a1_ = MFMA16(hc1, whF[3], a1_, 0, 0, 0);                                                \
      a2_ = MFMA16(FC0, wxF[4], a2_, 0, 0, 0);                                                \
      a2_ = MFMA16(FC1, wxF[5], a2_, 0, 0, 0);                                                \
      a2_ = MFMA16(hc0, whF[4], a2_, 0, 0, 0);                                                \
      a2_ = MFMA16(hc1, whF[5], a2_, 0, 0, 0);                                                \
      a3_ = MFMA16(FC0, wxF[6], a3_, 0, 0, 0);                                                \
      a3_ = MFMA16(FC1, wxF[7], a3_, 0, 0, 0);                                                \
      a3_ = MFMA16(hc0, whF[6], a3_, 0, 0, 0);                                                \
      a3_ = MFMA16(hc1, whF[7], a3_, 0, 0, 0);                                                \
      f32x4 pscc = sp4(0.f), pscv = sp4(0.f);                                                 \
      pscc = MFMA16(hc0, fA0, pscc, 0, 0, 0);                                                 \
      pscc = MFMA16(hc1, fA1, pscc, 0, 0, 0);                                                 \
      pscv = MFMA16(hv0, fB0, pscv, 0, 0, 0);                                                 \
      pscv = MFMA16(hv1, fB1, pscv, 0, 0, 0);                                                 \
      __builtin_amdgcn_s_setprio(0);                                                          \
      if (l4 < 2) {                                                                           \
        float4 gp4 = *(const float4*)&smf[(CKP) + (l4 << 2)];                                 \
        if (!sec) { CGELEM(0, HNEW) CGELEM(1, HNEW) }                                         \
        else      { CGELEM(2, HNEW) CGELEM(3, HNEW) }                                         \
      }                                                                                       \
    } else {                                                                                  \
      f32x4 a0_ = sp4(bgate[0]), a1_ = sp4(bgate[1]), a2_ = sp4(bgate[2]),                    \
            a3_ = sp4(bgate[3]);                                                              \
      __builtin_amdgcn_s_setprio(1);                                                          \
      a0_ = MFMA16(FC0, wxF[0], a0_, 0, 0, 0);                                                \
      a0_ = MFMA16(FC1, wxF[1], a0_, 0, 0, 0);                                                \
      a0_ = MFMA16(hv0, whF[0], a0_, 0, 0, 0);                                                \
      a0_ = MFMA16(hv1, whF[1], a0_, 0, 0, 0);                                                \
      a1_ = MFMA16(FC0, wxF[2], a1_, 0, 0, 0);                                                \
      a1_ = MFMA16(FC1, wxF[3], a1_, 0, 0, 0);                                                \
      a1_ = MFMA16(hv0, whF[2], a1_, 0, 0, 0);                                                \
      a1_ = MFMA16(hv1, whF[3], a1_, 0, 0, 0);                                                \
      a2_ = MFMA16(FC0, wxF[4], a2_, 0, 0, 0);                                                \
      a2_ = MFMA16(FC1, wxF[5], a2_, 0, 0, 0);                                                \
      a2_ = MFMA16(hv0, whF[4], a2_, 0, 0, 0);                                                \
      a2_ = MFMA16(hv1, whF[5], a2_, 0, 0, 0);                                                \
      a3_ = MFMA16(FC0, wxF[6], a3_, 0, 0, 0);                                                \
      a3_ = MFMA16(FC1, wxF[7], a3_, 0, 0, 0);                                                \
      a3_ = MFMA16(hv0, whF[6], a3_, 0, 0, 0);                                                \
      a3_ = MFMA16(hv1, whF[7], a3_, 0, 0, 0);                                                \
      f32x4 psvv = sp4(0.f);                                                                  \
      psvv = MFMA16(hv0, fA0, psvv, 0, 0, 0);                                                 \
      psvv = MFMA16(hv1, fA1, psvv, 0, 0, 0);                                                 \
      __builtin_amdgcn_s_setprio(0);                                                          \
      if ((T) >= 1) {                                                                         \
        f32x4 apv = sp4(b0u);                                                                 \
        apv = MFMA16(hv0, fC0, apv, 0, 0, 0);                                                 \
        apv = MFMA16(hv1, fC1, apv, 0, 0, 0);                                                 \
        if (l4 < 2) {                                                                         \
          if (!sec) { Y0VW(0) Y0VW(1) }                                                       \
          else      { Y0VW(2) Y0VW(3) }                                                       \
        }                                                                                     \
      }                                                                                       \
      if (!sec) { VGELEM(0) VGELEM(1) }                                                       \
      else      { VGELEM(2) VGELEM(3) }                                                       \
    }                                                                                         \
    {                                                                                         \
      const int tn_ = ((T) + 1 < TT) ? (T) + 1 : (TT - 1);                                    \
      union { uint4 u; half8 h; } u0_, u1_;                                                   \
      u0_.u = xfr[(tn_ << 7)];                                                                \
      u1_.u = xfr[(tn_ << 7) + 1];                                                            \
      FN0 = u0_.h;                                                                            \
      FN1 = u1_.h;                                                                            \
      if (wid == 0 && lane >= 32 && lane < 40)                                                \
        ckn = x[(size_t)(r0 + lane - 32) * ROWSTR + tn_ * XD + 64];                           \
    }                                                                                         \
    __syncthreads(); /* B1 */                                                                 \
    half8 hn0 = lda(smc, HNEW, 0, lane), hn1 = lda(smc, HNEW, 1, lane);                       \
    if (!cw) {                                                                                \
      f32x4 psvc = sp4(0.f);                                                                  \
      psvc = MFMA16(hn0, fB0, psvc, 0, 0, 0);                                                 \
      psvc = MFMA16(hn1, fB1, psvc, 0, 0, 0);                                                 \
      if (l4 < 2) {                                                                           \
        float4 g4 = *(const float4*)&smf[(CKC) + (l4 << 2)];                                  \
        if (!sec) { VSELEM(0, HVNEW) VSELEM(1, HVNEW) }                                       \
        else      { VSELEM(2, HVNEW) VSELEM(3, HVNEW) }                                       \
      }                                                                                       \
    } else {                                                                                  \
      f32x4 ap = sp4(b0u);                                                                    \
      ap = MFMA16(hn0, fC0, ap, 0, 0, 0);                                                     \
      ap = MFMA16(hn1, fC1, ap, 0, 0, 0);                                                     \
      if (l4 < 2) {                                                                           \
        if (!sec) { Y0CW(0, Y0W) Y0CW(1, Y0W) }                                               \
        else      { Y0CW(2, Y0W) Y0CW(3, Y0W) }                                               \
      }                                                                                       \
      if ((T) >= 1) {                                                                         \
        const int asrc = (w8 < 2) ? (Y0P) : L_Y0V;                                            \
        f32x4 ah = sp4(b1h);                                                                  \
        ah = MFMA16(lda(smc, asrc, 0, lane), fD0, ah, 0, 0, 0);                               \
        ah = MFMA16(lda(smc, asrc, 1, lane), fD1, ah, 0, 0, 0);                               \
        if (!sec) { HEADQ(0) HEADQ(1) }                                                       \
        else      { HEADQ(2) HEADQ(3) }                                                       \
      }                                                                                       \
    }                                                                                         \
    if (wid == 0 && lane >= 32 && lane < 40) smf[(CKP) + (lane - 32)] = ckn;                  \
    __syncthreads(); /* B2 */                                                                 \
  }

// ---- fused RNN: 8 rows/block, 256 blocks, 16 waves (dup pairs, q-split) ----
extern "C" __global__ void __launch_bounds__(1024, 1)
rnn_mfma(const float* __restrict__ x,
         const float* __restrict__ bxc, const float* __restrict__ bxv,
         const float* __restrict__ bpc0, const float* __restrict__ bpc1,
         const float* __restrict__ Wfcc, const float* __restrict__ bfcc,
         const float* __restrict__ bpv0, const float* __restrict__ bpv1,
         const float* __restrict__ Wfcv, const float* __restrict__ bfcv,
         const unsigned* __restrict__ ws, float* __restrict__ out) {
  extern __shared__ unsigned sm[];
  char* smc = (char*)sm;
  float* smf = (float*)sm;
  const int tid = threadIdx.x;
  const int lane = tid & 63, wid = tid >> 6;
  const int l15 = lane & 15, l4 = lane >> 4;
  const int w8 = wid & 7;
  const bool sec = wid >= 8;
  const int wq = w8 & 3;
  const bool cw = w8 < 4;
  const int r0 = blockIdx.x * 8;

  // zero all LDS (tiles/ck/part)
  for (int i = tid; i < L_TOT; i += 1024) sm[i] = 0;

  // per-wave constants
  float bgate[4];
#pragma unroll
  for (int m = 0; m < 4; ++m) bgate[m] = (cw ? bxc : bxv)[(wq + 4 * m) * 16 + l15];
  const float b0u = (cw ? bpc0 : bpv0)[16 * wq + l15];
  const float b1h = (w8 < 2 ? bpc1 : bpv1)[16 * (w8 & 1) + l15];
  const float wfh = (w8 < 2 ? Wfcc : Wfcv)[16 * (w8 & 1) + l15];
  const float bfc = bfcc[0], bfv = bfcv[0];

  // hoisted B-fragments: gate weights fully in registers
  half8 wxF[8], whF[8];
#pragma unroll
  for (int m = 0; m < 4; ++m) {
    wxF[2 * m] = ldg8(ws, cw ? GOFF_WXC : GOFF_WXV, wq + 4 * m, 0, lane);
    wxF[2 * m + 1] = ldg8(ws, cw ? GOFF_WXC : GOFF_WXV, wq + 4 * m, 1, lane);
    whF[2 * m] = ldg8(ws, cw ? GOFF_WHC : GOFF_WHV, wq + 4 * m, 0, lane);
    whF[2 * m + 1] = ldg8(ws, cw ? GOFF_WHC : GOFF_WHV, wq + 4 * m, 1, lane);
  }
  half8 fA0, fA1, fB0, fB1, fC0, fC1, fD0, fD1;
  if (cw) {
    fA0 = ldg8(ws, GOFF_SCC, wq, 0, lane); fA1 = ldg8(ws, GOFF_SCC, wq, 1, lane);
    fB0 = ldg8(ws, GOFF_SCV, wq, 0, lane); fB1 = ldg8(ws, GOFF_SCV, wq, 1, lane);
    fC0 = ldg8(ws, GOFF_PC0, wq, 0, lane); fC1 = ldg8(ws, GOFF_PC0, wq, 1, lane);
    const int hoff = (w8 < 2) ? GOFF_PC1 : GOFF_PV1;
    fD0 = ldg8(ws, hoff, w8 & 1, 0, lane); fD1 = ldg8(ws, hoff, w8 & 1, 1, lane);
  } else {
    fA0 = ldg8(ws, GOFF_SVV, wq, 0, lane); fA1 = ldg8(ws, GOFF_SVV, wq, 1, lane);
    fB0 = ldg8(ws, GOFF_SVC, wq, 0, lane); fB1 = ldg8(ws, GOFF_SVC, wq, 1, lane);
    fC0 = ldg8(ws, GOFF_PV0, wq, 0, lane); fC1 = ldg8(ws, GOFF_PV0, wq, 1, lane);
    fD0 = fA0; fD1 = fA1;  // unused by v-waves
  }

  // click(0) -> CK slot0 (slot1 stays 0 => g(-1)=0)
  if (wid == 0 && lane >= 32 && lane < 40)
    smf[L_CK + (lane - 32)] = x[(size_t)(r0 + lane - 32) * ROWSTR + 64];

  // feat A-frag stream (prepacked f16 by xpack)
  const uint4* xfr = (const uint4*)(ws + WS_X) + (size_t)blockIdx.x * 25600 + lane * 2;
  half8 fx0, fx1, fy0, fy1;
  {
    union { uint4 u; half8 h; } u0_, u1_;
    u0_.u = xfr[0];
    u1_.u = xfr[1];
    fx0 = u0_.h;
    fx1 = u1_.h;
  }

  float st[4] = {0.f, 0.f, 0.f, 0.f};     // s_c (c-waves) / s_v (v-waves), q-owned
  float hvold[4] = {0.f, 0.f, 0.f, 0.f};
  float fvv[4], ivv[4], ovv[4], gvv[4], psv[4];
  float ckn = 0.f;
  const int col2 = (16 * wq + l15) * 2;
  float2* o2 = (float2*)out;

  __syncthreads();

  for (int t = 0; t < TT; t += 2) {
    STEP(t,     L_HC0, L_HC1, L_HV0, L_HV1, L_Y0C0, L_Y0C1, L_CK + 8, L_CK + 0, fx0, fx1, fy0, fy1)
    STEP(t + 1, L_HC1, L_HC0, L_HV1, L_HV0, L_Y0C1, L_Y0C0, L_CK + 0, L_CK + 8, fy0, fy1, fx0, fx1)
  }

  // ---- epilogue: out(198), out(199) (primary waves only do the math) ----
  if (wid == 7 && lane < 8) {
    float pc = sigm(smf[L_PART + lane] + smf[L_PART + 8 + lane] + bfc);
    float pv = sigm(smf[L_PART + 16 + lane] + smf[L_PART + 24 + lane] + bfv);
    o2[(size_t)(r0 + lane) * TT + (TT - 2)] = make_float2(pc, pv * pc);
  }
  if (!cw && !sec) {  // pv0(199): h_v(199) in L_HV0
    f32x4 apv = sp4(b0u);
    apv = MFMA16(lda(smc, L_HV0, 0, lane), fC0, apv, 0, 0, 0);
    apv = MFMA16(lda(smc, L_HV0, 1, lane), fC1, apv, 0, 0, 0);
    if (l4 < 2) { Y0VW(0) Y0VW(1) Y0VW(2) Y0VW(3) }
  }
  __syncthreads();
  if (cw && !sec) {  // heads(199): y0c(199) in L_Y0C1
    const int asrc = (w8 < 2) ? L_Y0C1 : L_Y0V;
    f32x4 ah = sp4(b1h);
    ah = MFMA16(lda(smc, asrc, 0, lane), fD0, ah, 0, 0, 0);
    ah = MFMA16(lda(smc, asrc, 1, lane), fD1, ah, 0, 0, 0);
    HEADQ(0) HEADQ(1) HEADQ(2) HEADQ(3)
  }
  __syncthreads();
  if (wid == 0 && lane < 8) {
    float pc = sigm(smf[L_PART + lane] + smf[L_PART + 8 + lane] + bfc);
    float pv = sigm(smf[L_PART + 16 + lane] + smf[L_PART + 24 + lane] + bfv);
    o2[(size_t)(r0 + lane) * TT + (TT - 1)] = make_float2(pc, pv * pc);
  }
}

extern "C" void kernel_launch(void* const* d_in, const int* in_sizes, int n_in,
                              void* d_out, int out_size, void* d_ws, size_t ws_size,
                              hipStream_t stream) {
  const float* x    = (const float*)d_in[0];
  const float* Wxc  = (const float*)d_in[1];
  const float* bxc  = (const float*)d_in[2];
  const float* Whc  = (const float*)d_in[3];
  const float* Wxv  = (const float*)d_in[4];
  const float* bxv  = (const float*)d_in[5];
  const float* Whv  = (const float*)d_in[6];
  const float* Wscc = (const float*)d_in[7];
  const float* Wscv = (const float*)d_in[8];
  const float* Wsvv = (const float*)d_in[9];
  const float* Wsvc = (const float*)d_in[10];
  const float* Wpc0 = (const float*)d_in[11];
  const float* bpc0 = (const float*)d_in[12];
  const float* Wpc1 = (const float*)d_in[13];
  const float* bpc1 = (const float*)d_in[14];
  const float* Wfcc = (const float*)d_in[15];
  const float* bfcc = (const float*)d_in[16];
  const float* Wpv0 = (const float*)d_in[17];
  const float* bpv0 = (const float*)d_in[18];
  const float* Wpv1 = (const float*)d_in[19];
  const float* bpv1 = (const float*)d_in[20];
  const float* Wfcv = (const float*)d_in[21];
  const float* bfcv = (const float*)d_in[22];
  float* out = (float*)d_out;
  unsigned* wsbuf = (unsigned*)d_ws;

  prepack<<<184, 256, 0, stream>>>(Wxc, Wxv, Whc, Whv, Wscc, Wscv, Wsvv, Wsvc,
                                   Wpc0, Wpv0, Wpc1, Wpv1, wsbuf);
  xpack<<<256 * 200, 512, 0, stream>>>(x, wsbuf + WS_X);

  (void)hipFuncSetAttribute(reinterpret_cast<const void*>(rnn_mfma),
                            hipFuncAttributeMaxDynamicSharedMemorySize, L_TOT * 4);
  rnn_mfma<<<256, 1024, L_TOT * 4, stream>>>(
      x, bxc, bxv, bpc0, bpc1, Wfcc, bfcc, bpv0, bpv1, Wfcv, bfcv, wsbuf, out);
}

// Round 9
// 618.508 us; speedup vs baseline: 3.6219x; 3.6219x over previous
//
#include <hip/hip_runtime.h>

#define TT 200
#define XD 65
#define ROWSTR (TT * XD)  // 13000

typedef _Float16 h2 __attribute__((ext_vector_type(2)));
typedef _Float16 half8 __attribute__((ext_vector_type(8)));
typedef float f32x4 __attribute__((ext_vector_type(4)));

#define MFMA16 __builtin_amdgcn_mfma_f32_16x16x32_f16

// ---- ws dword offsets ----
#define GOFF_WXC 0
#define GOFF_WXV 8192
#define GOFF_WHC 16384
#define GOFF_WHV 24576
#define GOFF_SCC 32768
#define GOFF_SCV 34816
#define GOFF_SVV 36864
#define GOFF_SVC 38912
#define GOFF_PC0 40960
#define GOFF_PV0 43008
#define GOFF_PC1 45056
#define GOFF_PV1 46080
#define GTOT     47104
#define WS_X     47104ull                 // feat frags: 256 b * 2 G * 200 t * 512 dw
#define WS_H     (47104ull + 52428800ull) // h store: 200*2048*2*64 f16 = 26.2M dw

// ---- LDS (main): 8 tiles of 512 dw ([16 rows][64 f16] swizzled; rows 4-15 zero) ----
// hc[G][p] = G*1024 + p*512 ; hv[G][p] = 2048 + G*1024 + p*512
#define L_TOT 4096  // 16 KB

__device__ __forceinline__ unsigned pk(float lo, float hi) {
  union { h2 h; unsigned u; } c;
  c.h.x = (_Float16)lo;
  c.h.y = (_Float16)hi;
  return c.u;
}
__device__ __forceinline__ float fexp2(float x) {
#if __has_builtin(__builtin_amdgcn_exp2f)
  return __builtin_amdgcn_exp2f(x);
#else
  return __expf(x * 0.6931471805599453f);
#endif
}
__device__ __forceinline__ float frcp(float x) {
#if __has_builtin(__builtin_amdgcn_rcpf)
  return __builtin_amdgcn_rcpf(x);
#else
  return 1.0f / x;
#endif
}
__device__ __forceinline__ float sigm(float x) { return frcp(1.f + fexp2(x * -1.44269504f)); }
__device__ __forceinline__ float tanh_fast(float x) {
  return fmaf(2.f, frcp(1.f + fexp2(x * -2.88539008f)), -1.f);
}
__device__ __forceinline__ float leaky(float x) { return x > 0.0f ? x : 0.3f * x; }
__device__ __forceinline__ f32x4 sp4(float v) { f32x4 r = {v, v, v, v}; return r; }

__device__ __forceinline__ int swz(int b) { return b ^ ((b >> 3) & 0x70); }

// A-frag: row = lane&15, k = kh*32 + 8*(lane>>4) + i
__device__ __forceinline__ half8 lda(const char* smc, int dwoff, int kh, int lane) {
  int byte = (lane & 15) * 128 + kh * 64 + ((lane >> 4) << 4);
  union { uint4 u; half8 h; } c;
  c.u = *(const uint4*)(smc + (dwoff << 2) + swz(byte));
  return c.h;
}
// B-frag from global ws pool
__device__ __forceinline__ half8 ldg8(const unsigned* ws, int off, int n, int kh, int lane) {
  union { uint4 u; half8 h; } c;
  c.u = *(const uint4*)(ws + off + (((n * 2 + kh) * 64 + lane) << 2));
  return c.h;
}

// ---- prepack: f32 weights -> f16 B-fragment pools (unchanged, verified) ----
extern "C" __global__ void prepack(const float* __restrict__ Wxc, const float* __restrict__ Wxv,
                                   const float* __restrict__ Whc, const float* __restrict__ Whv,
                                   const float* __restrict__ Wscc, const float* __restrict__ Wscv,
                                   const float* __restrict__ Wsvv, const float* __restrict__ Wsvc,
                                   const float* __restrict__ Wpc0, const float* __restrict__ Wpv0,
                                   const float* __restrict__ Wpc1, const float* __restrict__ Wpv1,
                                   unsigned* __restrict__ wsout) {
  int idx = blockIdx.x * 256 + threadIdx.x;
  if (idx >= GTOT) return;
  const float* W; int base, ncol;
  if      (idx < GOFF_WXV) { W = Wxc;  base = GOFF_WXC; ncol = 256; }
  else if (idx < GOFF_WHC) { W = Wxv;  base = GOFF_WXV; ncol = 256; }
  else if (idx < GOFF_WHV) { W = Whc;  base = GOFF_WHC; ncol = 256; }
  else if (idx < GOFF_SCC) { W = Whv;  base = GOFF_WHV; ncol = 256; }
  else if (idx < GOFF_SCV) { W = Wscc; base = GOFF_SCC; ncol = 64; }
  else if (idx < GOFF_SVV) { W = Wscv; base = GOFF_SCV; ncol = 64; }
  else if (idx < GOFF_SVC) { W = Wsvv; base = GOFF_SVV; ncol = 64; }
  else if (idx < GOFF_PC0) { W = Wsvc; base = GOFF_SVC; ncol = 64; }
  else if (idx < GOFF_PV0) { W = Wpc0; base = GOFF_PC0; ncol = 64; }
  else if (idx < GOFF_PC1) { W = Wpv0; base = GOFF_PV0; ncol = 64; }
  else if (idx < GOFF_PV1) { W = Wpc1; base = GOFF_PC1; ncol = 32; }
  else                     { W = Wpv1; base = GOFF_PV1; ncol = 32; }
  int local = idx - base;
  int d = local & 3, lane = (local >> 2) & 63, nk = local >> 8;
  int kh = nk & 1, n = nk >> 1;
  int k0 = kh * 32 + ((lane >> 4) << 3) + (d << 1);
  int c = n * 16 + (lane & 15);
  wsout[idx] = pk(W[k0 * ncol + c], W[(k0 + 1) * ncol + c]);
}

// ---- xpack: feats -> f16 A-frag stream [b][G][t][512dw], row = b*8+G*4+(lane&3) ----
extern "C" __global__ void xpack(const float* __restrict__ x, unsigned* __restrict__ wsx) {
  int blk = blockIdx.x;  // 256*2*200
  int b = blk / 400, rem = blk - b * 400;
  int G = rem / 200, t = rem - G * 200;
  int tid = threadIdx.x;  // 512
  int lane = tid >> 3, d = tid & 7;
  int row = b * 8 + G * 4 + (lane & 3);
  int k = ((d & 4) ? 32 : 0) + ((lane >> 4) << 3) + ((d & 3) << 1);
  const float* p = x + (size_t)row * ROWSTR + t * XD + k;
  wsx[(size_t)blk * 512 + tid] = pk(p[0], p[1]);
}

// ---- elementwise sub-macros (literal Q) ----
#define CE(Q, GQ, G, M, HCN, STC, GPREV)                                                \
  {                                                                                     \
    bool gp = GPREV[Q] != 0.f;                                                          \
    float f_ = sigm(a0_[Q]), ii_ = sigm(a1_[Q]), o_ = sigm(a2_[Q]);                     \
    float gc_ = tanh_fast(a3_[Q]);                                                      \
    float sh_ = tanh_fast(gp ? pscv[Q] : pscc[Q]);                                      \
    float s_ = sh_ + ii_ * gc_ + (gp ? 0.f : f_ * STC[Q]);                              \
    STC[Q] = s_;                                                                        \
    float hc_ = o_ * tanh_fast(s_);                                                     \
    *(_Float16*)(smc + ((HCN) << 2) + swz((Q)*128 + col2)) = (_Float16)hc_;             \
    hws[(((size_t)(M)*2048 + r0 + (G)*4 + (Q)) * 2 + 0) * 64 + colu] = (_Float16)hc_;   \
    GPREV[Q] = ((GQ) >= 0.5f) ? 1.f : 0.f;                                              \
  }
#define VE(Q, GQ, G, M, HVN, STV, HVOLD)                                                \
  {                                                                                     \
    bool g_ = (GQ) >= 0.5f;                                                             \
    float fv_ = sigm(a0_[Q]), iv_ = sigm(a1_[Q]), ov_ = sigm(a2_[Q]);                   \
    float gv_ = tanh_fast(a3_[Q]);                                                      \
    float sh_ = tanh_fast(g_ ? psvv[Q] + psvc[Q] : psvv[Q]);                            \
    float s_ = sh_ + (g_ ? fv_ * STV[Q] + iv_ * gv_ : STV[Q]);                          \
    STV[Q] = s_;                                                                        \
    float hv_ = g_ ? ov_ * tanh_fast(s_) : HVOLD[Q];                                    \
    HVOLD[Q] = hv_;                                                                     \
    *(_Float16*)(smc + ((HVN) << 2) + swz((Q)*128 + col2)) = (_Float16)hv_;             \
    hws[(((size_t)(M)*2048 + r0 + (G)*4 + (Q)) * 2 + 1) * 64 + colu] = (_Float16)hv_;   \
  }

#define GATES16(AF0, AF1, H0, H1)                                                       \
  a0_ = MFMA16(AF0, wxF[0], a0_, 0, 0, 0); a0_ = MFMA16(AF1, wxF[1], a0_, 0, 0, 0);     \
  a0_ = MFMA16(H0, whF[0], a0_, 0, 0, 0);  a0_ = MFMA16(H1, whF[1], a0_, 0, 0, 0);      \
  a1_ = MFMA16(AF0, wxF[2], a1_, 0, 0, 0); a1_ = MFMA16(AF1, wxF[3], a1_, 0, 0, 0);     \
  a1_ = MFMA16(H0, whF[2], a1_, 0, 0, 0);  a1_ = MFMA16(H1, whF[3], a1_, 0, 0, 0);      \
  a2_ = MFMA16(AF0, wxF[4], a2_, 0, 0, 0); a2_ = MFMA16(AF1, wxF[5], a2_, 0, 0, 0);     \
  a2_ = MFMA16(H0, whF[4], a2_, 0, 0, 0);  a2_ = MFMA16(H1, whF[5], a2_, 0, 0, 0);      \
  a3_ = MFMA16(AF0, wxF[6], a3_, 0, 0, 0); a3_ = MFMA16(AF1, wxF[7], a3_, 0, 0, 0);     \
  a3_ = MFMA16(H0, whF[6], a3_, 0, 0, 0);  a3_ = MFMA16(H1, whF[7], a3_, 0, 0, 0);

// c-wave interval work: gates + scc/scv + c-elem for (G, M); prefetch (NG, NM)
#define CA_STEP(G, M, P, NG, NM, STC, GPREV)                                            \
  {                                                                                     \
    const int hco_ = (G)*1024 + ((P) ^ 1) * 512;                                        \
    const int hvo_ = 2048 + (G)*1024 + ((P) ^ 1) * 512;                                 \
    const int hcn_ = (G)*1024 + (P)*512;                                                \
    uint4 nf0_ = xfr[((NG)*TT + (NM)) << 7];                                            \
    uint4 nf1_ = xfr[(((NG)*TT + (NM)) << 7) + 1];                                      \
    float ng0_ = xck[((NG)*4 + 0) * ROWSTR + (NM)*XD];                                  \
    float ng1_ = xck[((NG)*4 + 1) * ROWSTR + (NM)*XD];                                  \
    float ng2_ = xck[((NG)*4 + 2) * ROWSTR + (NM)*XD];                                  \
    float ng3_ = xck[((NG)*4 + 3) * ROWSTR + (NM)*XD];                                  \
    half8 hc0 = lda(smc, hco_, 0, lane), hc1 = lda(smc, hco_, 1, lane);                 \
    half8 hv0 = lda(smc, hvo_, 0, lane), hv1 = lda(smc, hvo_, 1, lane);                 \
    union { uint4 u; half8 h; } cf0_, cf1_;                                             \
    cf0_.u = pf0; cf1_.u = pf1;                                                         \
    f32x4 a0_ = sp4(bgate[0]), a1_ = sp4(bgate[1]), a2_ = sp4(bgate[2]),                \
          a3_ = sp4(bgate[3]);                                                          \
    __builtin_amdgcn_s_setprio(1);                                                      \
    GATES16(cf0_.h, cf1_.h, hc0, hc1)                                                   \
    f32x4 pscc = sp4(0.f), pscv = sp4(0.f);                                             \
    pscc = MFMA16(hc0, fA0, pscc, 0, 0, 0); pscc = MFMA16(hc1, fA1, pscc, 0, 0, 0);     \
    pscv = MFMA16(hv0, fB0, pscv, 0, 0, 0); pscv = MFMA16(hv1, fB1, pscv, 0, 0, 0);     \
    __builtin_amdgcn_s_setprio(0);                                                      \
    if (l4 == 0) {                                                                      \
      CE(0, gq0, G, M, hcn_, STC, GPREV)                                                \
      CE(1, gq1, G, M, hcn_, STC, GPREV)                                                \
      CE(2, gq2, G, M, hcn_, STC, GPREV)                                                \
      CE(3, gq3, G, M, hcn_, STC, GPREV)                                                \
    }                                                                                   \
    pf0 = nf0_; pf1 = nf1_;                                                             \
    gq0 = ng0_; gq1 = ng1_; gq2 = ng2_; gq3 = ng3_;                                     \
  }

// v-wave interval work: v-gates + svv + svc + v-elem for (G, M); prefetch (NG, NM)
#define V_STEP(G, M, P, NG, NM, STV, HVOLD)                                             \
  {                                                                                     \
    const int hvo_ = 2048 + (G)*1024 + ((P) ^ 1) * 512;                                 \
    const int hvn_ = 2048 + (G)*1024 + (P)*512;                                         \
    const int hcc_ = (G)*1024 + (P)*512;                                                \
    uint4 nf0_ = xfr[((NG)*TT + (NM)) << 7];                                            \
    uint4 nf1_ = xfr[(((NG)*TT + (NM)) << 7) + 1];                                      \
    float ng0_ = xck[((NG)*4 + 0) * ROWSTR + (NM)*XD];                                  \
    float ng1_ = xck[((NG)*4 + 1) * ROWSTR + (NM)*XD];                                  \
    float ng2_ = xck[((NG)*4 + 2) * ROWSTR + (NM)*XD];                                  \
    float ng3_ = xck[((NG)*4 + 3) * ROWSTR + (NM)*XD];                                  \
    half8 hv0 = lda(smc, hvo_, 0, lane), hv1 = lda(smc, hvo_, 1, lane);                 \
    half8 hn0 = lda(smc, hcc_, 0, lane), hn1 = lda(smc, hcc_, 1, lane);                 \
    union { uint4 u; half8 h; } cf0_, cf1_;                                             \
    cf0_.u = pf0; cf1_.u = pf1;                                                         \
    f32x4 a0_ = sp4(bgate[0]), a1_ = sp4(bgate[1]), a2_ = sp4(bgate[2]),                \
          a3_ = sp4(bgate[3]);                                                          \
    __builtin_amdgcn_s_setprio(1);                                                      \
    GATES16(cf0_.h, cf1_.h, hv0, hv1)                                                   \
    f32x4 psvv = sp4(0.f), psvc = sp4(0.f);                                             \
    psvv = MFMA16(hv0, fA0, psvv, 0, 0, 0); psvv = MFMA16(hv1, fA1, psvv, 0, 0, 0);     \
    psvc = MFMA16(hn0, fB0, psvc, 0, 0, 0); psvc = MFMA16(hn1, fB1, psvc, 0, 0, 0);     \
    __builtin_amdgcn_s_setprio(0);                                                      \
    if (l4 == 0) {                                                                      \
      VE(0, gq0, G, M, hvn_, STV, HVOLD)                                                \
      VE(1, gq1, G, M, hvn_, STV, HVOLD)                                                \
      VE(2, gq2, G, M, hvn_, STV, HVOLD)                                                \
      VE(3, gq3, G, M, hvn_, STV, HVOLD)                                                \
    }                                                                                   \
    pf0 = nf0_; pf1 = nf1_;                                                             \
    gq0 = ng0_; gq1 = ng1_; gq2 = ng2_; gq3 = ng3_;                                     \
  }

// ---- main recurrence: 8 rows (2 groups of 4), 256 blocks, 8 waves, 1 barrier/interval ----
extern "C" __global__ void __launch_bounds__(512, 1)
rnn_pipe(const float* __restrict__ x,
         const float* __restrict__ bxc, const float* __restrict__ bxv,
         unsigned* __restrict__ ws) {
  extern __shared__ unsigned sm[];
  char* smc = (char*)sm;
  const int tid = threadIdx.x;
  const int lane = tid & 63, wid = tid >> 6;
  const int l15 = lane & 15, l4 = lane >> 4;
  const int wq = wid & 3;
  const bool cw = wid < 4;
  const int r0 = blockIdx.x * 8;

  for (int i = tid; i < L_TOT; i += 512) sm[i] = 0;

  float bgate[4];
#pragma unroll
  for (int m = 0; m < 4; ++m) bgate[m] = (cw ? bxc : bxv)[(wq + 4 * m) * 16 + l15];

  half8 wxF[8], whF[8];
#pragma unroll
  for (int m = 0; m < 4; ++m) {
    wxF[2 * m] = ldg8(ws, cw ? GOFF_WXC : GOFF_WXV, wq + 4 * m, 0, lane);
    wxF[2 * m + 1] = ldg8(ws, cw ? GOFF_WXC : GOFF_WXV, wq + 4 * m, 1, lane);
    whF[2 * m] = ldg8(ws, cw ? GOFF_WHC : GOFF_WHV, wq + 4 * m, 0, lane);
    whF[2 * m + 1] = ldg8(ws, cw ? GOFF_WHC : GOFF_WHV, wq + 4 * m, 1, lane);
  }
  half8 fA0, fA1, fB0, fB1;
  if (cw) {
    fA0 = ldg8(ws, GOFF_SCC, wq, 0, lane); fA1 = ldg8(ws, GOFF_SCC, wq, 1, lane);
    fB0 = ldg8(ws, GOFF_SCV, wq, 0, lane); fB1 = ldg8(ws, GOFF_SCV, wq, 1, lane);
  } else {
    fA0 = ldg8(ws, GOFF_SVV, wq, 0, lane); fA1 = ldg8(ws, GOFF_SVV, wq, 1, lane);
    fB0 = ldg8(ws, GOFF_SVC, wq, 0, lane); fB1 = ldg8(ws, GOFF_SVC, wq, 1, lane);
  }

  const uint4* xfr = (const uint4*)(ws + WS_X) + (size_t)blockIdx.x * (2 * TT * 128) + lane * 2;
  const float* xck = x + (size_t)r0 * ROWSTR + 64;
  _Float16* hws = (_Float16*)(ws + WS_H);
  const int col2 = (16 * wq + l15) * 2;
  const int colu = 16 * wq + l15;

  float stc0[4] = {0, 0, 0, 0}, stc1[4] = {0, 0, 0, 0};
  float gprev0[4] = {0, 0, 0, 0}, gprev1[4] = {0, 0, 0, 0};
  float stv0[4] = {0, 0, 0, 0}, stv1[4] = {0, 0, 0, 0};
  float hvo0[4] = {0, 0, 0, 0}, hvo1[4] = {0, 0, 0, 0};

  // prologue prefetch: (G1, 0) for both roles
  uint4 pf0 = xfr[TT << 7];
  uint4 pf1 = xfr[(TT << 7) + 1];
  float gq0 = xck[4 * ROWSTR], gq1 = xck[5 * ROWSTR], gq2 = xck[6 * ROWSTR], gq3 = xck[7 * ROWSTR];

  __syncthreads();

  for (int m = 0; m < TT; m += 2) {
    // interval j=2m: CA(G1,m) | V(G0,m-1)
    if (cw) { CA_STEP(1, m, 0, 0, m, stc1, gprev1) }
    else if (m > 0) { V_STEP(0, m - 1, 1, 1, m, stv0, hvo0) }
    __syncthreads();
    // interval j=2m+1: CA(G0,m) | V(G1,m)
    if (cw) { CA_STEP(0, m, 0, 1, m + 1, stc0, gprev0) }
    else { V_STEP(1, m, 0, 0, m, stv1, hvo1) }
    __syncthreads();
    // interval j=2m+2: CA(G1,m+1) | V(G0,m)
    if (cw) { CA_STEP(1, m + 1, 1, 0, m + 1, stc1, gprev1) }
    else { V_STEP(0, m, 0, 1, m + 1, stv0, hvo0) }
    __syncthreads();
    // interval j=2m+3: CA(G0,m+1) | V(G1,m+1)
    if (cw) { CA_STEP(0, m + 1, 1, 1, (m + 2 < TT ? m + 2 : TT - 1), stc0, gprev0) }
    else { V_STEP(1, m + 1, 1, 0, m + 1, stv1, hvo1) }
    __syncthreads();
  }
  // epilogue: V(G0, 199)
  if (!cw) { V_STEP(0, TT - 1, 1, 0, TT - 1, stv0, hvo0) }
}

// ---- heads: batched MLP over all (t, row) — no recurrence ----
extern "C" __global__ void __launch_bounds__(256, 1)
heads(const unsigned* __restrict__ ws,
      const float* __restrict__ bpc0, const float* __restrict__ bpc1,
      const float* __restrict__ Wfcc, const float* __restrict__ bfcc,
      const float* __restrict__ bpv0, const float* __restrict__ bpv1,
      const float* __restrict__ Wfcv, const float* __restrict__ bfcv,
      float* __restrict__ out) {
  __shared__ unsigned ysm[2048];  // 4 waves x 512 dw
  char* smc = (char*)ysm;
  const int tid = threadIdx.x, lane = tid & 63, wvl = tid >> 6;
  const int l15 = lane & 15, l4 = lane >> 4;
  const int ybase = wvl * 512;
  const size_t cb = ((size_t)blockIdx.x * 4 + wvl) * 16;

  half8 pc0F[8], pv0F[8];
#pragma unroll
  for (int n = 0; n < 4; ++n) {
    pc0F[2 * n] = ldg8(ws, GOFF_PC0, n, 0, lane); pc0F[2 * n + 1] = ldg8(ws, GOFF_PC0, n, 1, lane);
    pv0F[2 * n] = ldg8(ws, GOFF_PV0, n, 0, lane); pv0F[2 * n + 1] = ldg8(ws, GOFF_PV0, n, 1, lane);
  }
  half8 pc1F[4], pv1F[4];
#pragma unroll
  for (int n = 0; n < 2; ++n) {
    pc1F[2 * n] = ldg8(ws, GOFF_PC1, n, 0, lane); pc1F[2 * n + 1] = ldg8(ws, GOFF_PC1, n, 1, lane);
    pv1F[2 * n] = ldg8(ws, GOFF_PV1, n, 0, lane); pv1F[2 * n + 1] = ldg8(ws, GOFF_PV1, n, 1, lane);
  }
  float b0c[4], b0v[4];
#pragma unroll
  for (int n = 0; n < 4; ++n) { b0c[n] = bpc0[n * 16 + l15]; b0v[n] = bpv0[n * 16 + l15]; }
  float b1c[2], b1v[2], wfc2[2], wfv2[2];
#pragma unroll
  for (int n = 0; n < 2; ++n) {
    b1c[n] = bpc1[n * 16 + l15]; wfc2[n] = Wfcc[n * 16 + l15];
    b1v[n] = bpv1[n * 16 + l15]; wfv2[n] = Wfcv[n * 16 + l15];
  }
  const float bfc = bfcc[0], bfv = bfcv[0];
  const _Float16* hsrc = (const _Float16*)(ws + WS_H);
  float2* o2 = (float2*)out;

  float pc_[4], pv_[4];
#pragma unroll
  for (int side = 0; side < 2; ++side) {
    union { uint4 u; half8 h; } A0, A1;
    A0.u = *(const uint4*)&hsrc[((cb + l15) * 2 + side) * 64 + (l4 << 3)];
    A1.u = *(const uint4*)&hsrc[((cb + l15) * 2 + side) * 64 + 32 + (l4 << 3)];
    f32x4 ac[4];
#pragma unroll
    for (int n = 0; n < 4; ++n) {
      ac[n] = sp4(side ? b0v[n] : b0c[n]);
      ac[n] = MFMA16(A0.h, side ? pv0F[2 * n] : pc0F[2 * n], ac[n], 0, 0, 0);
      ac[n] = MFMA16(A1.h, side ? pv0F[2 * n + 1] : pc0F[2 * n + 1], ac[n], 0, 0, 0);
    }
    // y0 -> LDS (swizzled A-tile), then A-frag read (same wave, in-order DS)
#pragma unroll
    for (int n = 0; n < 4; ++n)
#pragma unroll
      for (int q = 0; q < 4; ++q)
        *(_Float16*)(smc + (ybase << 2) + swz((l4 * 4 + q) * 128 + (n * 16 + l15) * 2)) =
            (_Float16)leaky(ac[n][q]);
    half8 ya0 = lda(smc, ybase, 0, lane), ya1 = lda(smc, ybase, 1, lane);
    f32x4 c0 = sp4(side ? b1v[0] : b1c[0]), c1 = sp4(side ? b1v[1] : b1c[1]);
    c0 = MFMA16(ya0, side ? pv1F[0] : pc1F[0], c0, 0, 0, 0);
    c0 = MFMA16(ya1, side ? pv1F[1] : pc1F[1], c0, 0, 0, 0);
    c1 = MFMA16(ya0, side ? pv1F[2] : pc1F[2], c1, 0, 0, 0);
    c1 = MFMA16(ya1, side ? pv1F[3] : pc1F[3], c1, 0, 0, 0);
#pragma unroll
    for (int q = 0; q < 4; ++q) {
      float tq = leaky(c0[q]) * (side ? wfv2[0] : wfc2[0]) +
                 leaky(c1[q]) * (side ? wfv2[1] : wfc2[1]);
      tq += __shfl_xor(tq, 1, 64);
      tq += __shfl_xor(tq, 2, 64);
      tq += __shfl_xor(tq, 4, 64);
      tq += __shfl_xor(tq, 8, 64);
      float p = sigm(tq + (side ? bfv : bfc));
      if (side) pv_[q] = p; else pc_[q] = p;
    }
  }
  if (l15 == 0) {
#pragma unroll
    for (int q = 0; q < 4; ++q) {
      size_t combo = cb + l4 * 4 + q;
      int t = (int)(combo >> 11);
      int row = (int)(combo & 2047);
      o2[(size_t)row * TT + t] = make_float2(pc_[q], pv_[q] * pc_[q]);
    }
  }
}

extern "C" void kernel_launch(void* const* d_in, const int* in_sizes, int n_in,
                              void* d_out, int out_size, void* d_ws, size_t ws_size,
                              hipStream_t stream) {
  const float* x    = (const float*)d_in[0];
  const float* Wxc  = (const float*)d_in[1];
  const float* bxc  = (const float*)d_in[2];
  const float* Whc  = (const float*)d_in[3];
  const float* Wxv  = (const float*)d_in[4];
  const float* bxv  = (const float*)d_in[5];
  const float* Whv  = (const float*)d_in[6];
  const float* Wscc = (const float*)d_in[7];
  const float* Wscv = (const float*)d_in[8];
  const float* Wsvv = (const float*)d_in[9];
  const float* Wsvc = (const float*)d_in[10];
  const float* Wpc0 = (const float*)d_in[11];
  const float* bpc0 = (const float*)d_in[12];
  const float* Wpc1 = (const float*)d_in[13];
  const float* bpc1 = (const float*)d_in[14];
  const float* Wfcc = (const float*)d_in[15];
  const float* bfcc = (const float*)d_in[16];
  const float* Wpv0 = (const float*)d_in[17];
  const float* bpv0 = (const float*)d_in[18];
  const float* Wpv1 = (const float*)d_in[19];
  const float* bpv1 = (const float*)d_in[20];
  const float* Wfcv = (const float*)d_in[21];
  const float* bfcv = (const float*)d_in[22];
  float* out = (float*)d_out;
  unsigned* wsbuf = (unsigned*)d_ws;

  prepack<<<184, 256, 0, stream>>>(Wxc, Wxv, Whc, Whv, Wscc, Wscv, Wsvv, Wsvc,
                                   Wpc0, Wpv0, Wpc1, Wpv1, wsbuf);
  xpack<<<256 * 2 * 200, 512, 0, stream>>>(x, wsbuf + WS_X);

  (void)hipFuncSetAttribute(reinterpret_cast<const void*>(rnn_pipe),
                            hipFuncAttributeMaxDynamicSharedMemorySize, L_TOT * 4);
  rnn_pipe<<<256, 512, L_TOT * 4, stream>>>(x, bxc, bxv, wsbuf);

  heads<<<6400, 256, 0, stream>>>(wsbuf, bpc0, bpc1, Wfcc, bfcc, bpv0, bpv1, Wfcv, bfcv, out);
}

// Round 10
// 392.764 us; speedup vs baseline: 5.7037x; 1.5748x over previous
//
#include <hip/hip_runtime.h>

#define TT 200
#define XD 65
#define ROWSTR (TT * XD)  // 13000

typedef _Float16 h2 __attribute__((ext_vector_type(2)));
typedef _Float16 half8 __attribute__((ext_vector_type(8)));
typedef float f32x4 __attribute__((ext_vector_type(4)));

#define MFMA16 __builtin_amdgcn_mfma_f32_16x16x32_f16

// ---- ws dword offsets: prepacked f16 B-fragment pools + feat A-frag stream ----
#define GOFF_WXC 0
#define GOFF_WXV 8192
#define GOFF_WHC 16384
#define GOFF_WHV 24576
#define GOFF_SCC 32768
#define GOFF_SCV 34816
#define GOFF_SVV 36864
#define GOFF_SVC 38912
#define GOFF_PC0 40960
#define GOFF_PV0 43008
#define GOFF_PC1 45056
#define GOFF_PV1 46080
#define GTOT     47104
#define WS_X     47104ull  // feats: 256 b * 200 t * 256 dw (compact f16 pairs)

// ---- LDS dword offsets (tiles only) ----
#define L_HC0 0      // 512-dw tiles: [16 rows][64 f16] swizzled (rows 8-15 stay 0)
#define L_HC1 512
#define L_HV0 1024
#define L_HV1 1536
#define L_Y0C0 2048
#define L_Y0C1 2560
#define L_Y0V  3072
#define L_PART 3584  // 32 floats
#define L_TOT  3616  // 14,464 B

__device__ __forceinline__ unsigned pk(float lo, float hi) {
  union { h2 h; unsigned u; } c;
  c.h.x = (_Float16)lo;
  c.h.y = (_Float16)hi;
  return c.u;
}

__device__ __forceinline__ float fexp2(float x) {
#if __has_builtin(__builtin_amdgcn_exp2f)
  return __builtin_amdgcn_exp2f(x);
#else
  return __expf(x * 0.6931471805599453f);
#endif
}
__device__ __forceinline__ float frcp(float x) {
#if __has_builtin(__builtin_amdgcn_rcpf)
  return __builtin_amdgcn_rcpf(x);
#else
  return 1.0f / x;
#endif
}
__device__ __forceinline__ float sigm(float x) { return frcp(1.f + fexp2(x * -1.44269504f)); }
__device__ __forceinline__ float tanh_fast(float x) {
  return fmaf(2.f, frcp(1.f + fexp2(x * -2.88539008f)), -1.f);
}
__device__ __forceinline__ float leaky(float x) { return x > 0.0f ? x : 0.3f * x; }
__device__ __forceinline__ f32x4 sp4(float v) { f32x4 r = {v, v, v, v}; return r; }

// XOR swizzle within a [16][128B] tile
__device__ __forceinline__ int swz(int b) { return b ^ ((b >> 3) & 0x70); }

// A-frag: row = lane&15 (rows 8-15 read zeros), k = kh*32 + 8*(lane>>4) + i
__device__ __forceinline__ half8 lda(const char* smc, int dwoff, int kh, int lane) {
  int byte = (lane & 15) * 128 + kh * 64 + ((lane >> 4) << 4);
  union { uint4 u; half8 h; } c;
  c.u = *(const uint4*)(smc + (dwoff << 2) + swz(byte));
  return c.h;
}
// B-frag from global ws pool
__device__ __forceinline__ half8 ldg8(const unsigned* ws, int off, int n, int kh, int lane) {
  union { uint4 u; half8 h; } c;
  c.u = *(const uint4*)(ws + off + (((n * 2 + kh) * 64 + lane) << 2));
  return c.h;
}

// ---- prepack: f32 weights -> f16 B-fragment pools in ws (verified) ----
extern "C" __global__ void prepack(const float* __restrict__ Wxc, const float* __restrict__ Wxv,
                                   const float* __restrict__ Whc, const float* __restrict__ Whv,
                                   const float* __restrict__ Wscc, const float* __restrict__ Wscv,
                                   const float* __restrict__ Wsvv, const float* __restrict__ Wsvc,
                                   const float* __restrict__ Wpc0, const float* __restrict__ Wpv0,
                                   const float* __restrict__ Wpc1, const float* __restrict__ Wpv1,
                                   unsigned* __restrict__ wsout) {
  int idx = blockIdx.x * 256 + threadIdx.x;
  if (idx >= GTOT) return;
  const float* W; int base, ncol;
  if      (idx < GOFF_WXV) { W = Wxc;  base = GOFF_WXC; ncol = 256; }
  else if (idx < GOFF_WHC) { W = Wxv;  base = GOFF_WXV; ncol = 256; }
  else if (idx < GOFF_WHV) { W = Whc;  base = GOFF_WHC; ncol = 256; }
  else if (idx < GOFF_SCC) { W = Whv;  base = GOFF_WHV; ncol = 256; }
  else if (idx < GOFF_SCV) { W = Wscc; base = GOFF_SCC; ncol = 64; }
  else if (idx < GOFF_SVV) { W = Wscv; base = GOFF_SCV; ncol = 64; }
  else if (idx < GOFF_SVC) { W = Wsvv; base = GOFF_SVV; ncol = 64; }
  else if (idx < GOFF_PC0) { W = Wsvc; base = GOFF_SVC; ncol = 64; }
  else if (idx < GOFF_PV0) { W = Wpc0; base = GOFF_PC0; ncol = 64; }
  else if (idx < GOFF_PC1) { W = Wpv0; base = GOFF_PV0; ncol = 64; }
  else if (idx < GOFF_PV1) { W = Wpc1; base = GOFF_PC1; ncol = 32; }
  else                     { W = Wpv1; base = GOFF_PV1; ncol = 32; }
  int local = idx - base;
  int d = local & 3, lane = (local >> 2) & 63, nk = local >> 8;
  int kh = nk & 1, n = nk >> 1;
  int k0 = kh * 32 + ((lane >> 4) << 3) + (d << 1);
  int c = n * 16 + (lane & 15);
  wsout[idx] = pk(W[k0 * ncol + c], W[(k0 + 1) * ncol + c]);
}

// ---- xpack: feats -> compact f16 pair stream [b][t][row8][32dw] ----
// main-loop lane (row = lane&7, kgrp = lane>>4) reads uint4 at row*32 + kgrp*4 + kh*16
extern "C" __global__ void xpack(const float* __restrict__ x, unsigned* __restrict__ wsx) {
  int t = blockIdx.x;   // 200
  int b = blockIdx.y;   // 256
  int tid = threadIdx.x;  // 256
  int row8 = tid >> 5, kdw = tid & 31;
  const float* p = x + (size_t)(b * 8 + row8) * ROWSTR + t * XD + kdw * 2;
  wsx[((size_t)b * TT + t) * 256 + tid] = pk(p[0], p[1]);
}

// One RNN step; parity constants compile-time via 2x-unrolled caller.
// FC0/FC1: current feats A-frags. FN0/FN1: next-step frags (written here).
#define STEP(T, HCUR, HNEW, HVCUR, HVNEW, Y0W, Y0P, FC0, FC1, FN0, FN1)                       \
  {                                                                                           \
    if ((T) >= 2 && wid == 7 && lane < 8) {                                                   \
      float pc = sigm(smf[L_PART + lane] + smf[L_PART + 8 + lane] + bfc);                     \
      float pv = sigm(smf[L_PART + 16 + lane] + smf[L_PART + 24 + lane] + bfv);               \
      o2[(size_t)(r0 + lane) * TT + ((T) - 2)] = make_float2(pc, pv * pc);                    \
    }                                                                                         \
    half8 hv0 = lda(smc, HVCUR, 0, lane), hv1 = lda(smc, HVCUR, 1, lane);                     \
    if (cw) {                                                                                 \
      half8 hc0 = lda(smc, HCUR, 0, lane), hc1 = lda(smc, HCUR, 1, lane);                     \
      f32x4 a0_ = sp4(bgate[0]), a1_ = sp4(bgate[1]), a2_ = sp4(bgate[2]),                    \
            a3_ = sp4(bgate[3]);                                                              \
      __builtin_amdgcn_s_setprio(1);                                                          \
      a0_ = MFMA16(FC0, wxF[0], a0_, 0, 0, 0);                                                \
      a0_ = MFMA16(FC1, wxF[1], a0_, 0, 0, 0);                                                \
      a0_ = MFMA16(hc0, whF[0], a0_, 0, 0, 0);                                                \
      a0_ = MFMA16(hc1, whF[1], a0_, 0, 0, 0);                                                \
      a1_ = MFMA16(FC0, wxF[2], a1_, 0, 0, 0);                                                \
      a1_ = MFMA16(FC1, wxF[3], a1_, 0, 0, 0);                                                \
      a1_ = MFMA16(hc0, whF[2], a1_, 0, 0, 0);                                                \
      a1_ = MFMA16(hc1, whF[3], a1_, 0, 0, 0);                                                \
      a2_ = MFMA16(FC0, wxF[4], a2_, 0, 0, 0);                                                \
      a2_ = MFMA16(FC1, wxF[5], a2_, 0, 0, 0);                                                \
      a2_ = MFMA16(hc0, whF[4], a2_, 0, 0, 0);                                                \
      a2_ = MFMA16(hc1, whF[5], a2_, 0, 0, 0);                                                \
      a3_ = MFMA16(FC0, wxF[6], a3_, 0, 0, 0);                                                \
      a3_ = MFMA16(FC1, wxF[7], a3_, 0, 0, 0);                                                \
      a3_ = MFMA16(hc0, whF[6], a3_, 0, 0, 0);                                                \
      a3_ = MFMA16(hc1, whF[7], a3_, 0, 0, 0);                                                \
      f32x4 pscc = sp4(0.f), pscv = sp4(0.f);                                                 \
      pscc = MFMA16(hc0, fA0, pscc, 0, 0, 0);                                                 \
      pscc = MFMA16(hc1, fA1, pscc, 0, 0, 0);                                                 \
      pscv = MFMA16(hv0, fB0, pscv, 0, 0, 0);                                                 \
      pscv = MFMA16(hv1, fB1, pscv, 0, 0, 0);                                                 \
      __builtin_amdgcn_s_setprio(0);                                                          \
      if (l4 < 2) {                                                                           \
        _Pragma("unroll") for (int q = 0; q < 4; ++q) {                                       \
          bool gp = gprev[q] >= 0.5f;                                                         \
          float f = sigm(a0_[q]), ii = sigm(a1_[q]), o = sigm(a2_[q]);                        \
          float gc = tanh_fast(a3_[q]);                                                       \
          float sh = tanh_fast(gp ? pscv[q] : pscc[q]);                                       \
          float s = sh + ii * gc + (gp ? 0.f : f * st[q]);                                    \
          st[q] = s;                                                                          \
          float hcn = o * tanh_fast(s);                                                       \
          *(_Float16*)(smc + ((HNEW) << 2) + swz((l4 * 4 + q) * 128 + col2)) = (_Float16)hcn; \
        }                                                                                     \
      }                                                                                       \
    } else {                                                                                  \
      f32x4 a0_ = sp4(bgate[0]), a1_ = sp4(bgate[1]), a2_ = sp4(bgate[2]),                    \
            a3_ = sp4(bgate[3]);                                                              \
      __builtin_amdgcn_s_setprio(1);                                                          \
      a0_ = MFMA16(FC0, wxF[0], a0_, 0, 0, 0);                                                \
      a0_ = MFMA16(FC1, wxF[1], a0_, 0, 0, 0);                                                \
      a0_ = MFMA16(hv0, whF[0], a0_, 0, 0, 0);                                                \
      a0_ = MFMA16(hv1, whF[1], a0_, 0, 0, 0);                                                \
      a1_ = MFMA16(FC0, wxF[2], a1_, 0, 0, 0);                                                \
      a1_ = MFMA16(FC1, wxF[3], a1_, 0, 0, 0);                                                \
      a1_ = MFMA16(hv0, whF[2], a1_, 0, 0, 0);                                                \
      a1_ = MFMA16(hv1, whF[3], a1_, 0, 0, 0);                                                \
      a2_ = MFMA16(FC0, wxF[4], a2_, 0, 0, 0);                                                \
      a2_ = MFMA16(FC1, wxF[5], a2_, 0, 0, 0);                                                \
      a2_ = MFMA16(hv0, whF[4], a2_, 0, 0, 0);                                                \
      a2_ = MFMA16(hv1, whF[5], a2_, 0, 0, 0);                                                \
      a3_ = MFMA16(FC0, wxF[6], a3_, 0, 0, 0);                                                \
      a3_ = MFMA16(FC1, wxF[7], a3_, 0, 0, 0);                                                \
      a3_ = MFMA16(hv0, whF[6], a3_, 0, 0, 0);                                                \
      a3_ = MFMA16(hv1, whF[7], a3_, 0, 0, 0);                                                \
      f32x4 psvv = sp4(0.f);                                                                  \
      psvv = MFMA16(hv0, fA0, psvv, 0, 0, 0);                                                 \
      psvv = MFMA16(hv1, fA1, psvv, 0, 0, 0);                                                 \
      __builtin_amdgcn_s_setprio(0);                                                          \
      if ((T) >= 1) {                                                                         \
        f32x4 apv = sp4(b0u);                                                                 \
        apv = MFMA16(hv0, fC0, apv, 0, 0, 0);                                                 \
        apv = MFMA16(hv1, fC1, apv, 0, 0, 0);                                                 \
        if (l4 < 2) {                                                                         \
          _Pragma("unroll") for (int q = 0; q < 4; ++q)                                       \
              *(_Float16*)(smc + (L_Y0V << 2) + swz((l4 * 4 + q) * 128 + col2)) =             \
                  (_Float16)leaky(apv[q]);                                                    \
        }                                                                                     \
      }                                                                                       \
      _Pragma("unroll") for (int q = 0; q < 4; ++q) {                                         \
        fvv[q] = sigm(a0_[q]);                                                                \
        ivv[q] = sigm(a1_[q]);                                                                \
        ovv[q] = sigm(a2_[q]);                                                                \
        gvv[q] = tanh_fast(a3_[q]);                                                           \
        psv[q] = psvv[q];                                                                     \
      }                                                                                       \
    }                                                                                         \
    {                                                                                         \
      const int tn_ = ((T) + 1 < TT) ? (T) + 1 : (TT - 1);                                    \
      union { uint4 u; half8 h; } u0_, u1_;                                                   \
      u0_.u = xfr[tn_ * 64];                                                                  \
      u1_.u = xfr[tn_ * 64 + 4];                                                              \
      FN0 = u0_.h;                                                                            \
      FN1 = u1_.h;                                                                            \
      gnext[0] = xck[0 * ROWSTR + tn_ * XD];                                                  \
      gnext[1] = xck[1 * ROWSTR + tn_ * XD];                                                  \
      gnext[2] = xck[2 * ROWSTR + tn_ * XD];                                                  \
      gnext[3] = xck[3 * ROWSTR + tn_ * XD];                                                  \
    }                                                                                         \
    __syncthreads(); /* B1 */                                                                 \
    half8 hn0 = lda(smc, HNEW, 0, lane), hn1 = lda(smc, HNEW, 1, lane);                       \
    if (!cw) {                                                                                \
      f32x4 psvc = sp4(0.f);                                                                  \
      psvc = MFMA16(hn0, fB0, psvc, 0, 0, 0);                                                 \
      psvc = MFMA16(hn1, fB1, psvc, 0, 0, 0);                                                 \
      if (l4 < 2) {                                                                           \
        _Pragma("unroll") for (int q = 0; q < 4; ++q) {                                       \
          bool g = gcur[q] >= 0.5f;                                                           \
          float sh = tanh_fast(g ? psv[q] + psvc[q] : psv[q]);                                \
          float s = sh + (g ? fvv[q] * st[q] + ivv[q] * gvv[q] : st[q]);                      \
          st[q] = s;                                                                          \
          float hvn = g ? ovv[q] * tanh_fast(s) : hvold[q];                                   \
          hvold[q] = hvn;                                                                     \
          *(_Float16*)(smc + ((HVNEW) << 2) + swz((l4 * 4 + q) * 128 + col2)) = (_Float16)hvn;\
        }                                                                                     \
      }                                                                                       \
    } else {                                                                                  \
      f32x4 ap = sp4(b0u);                                                                    \
      ap = MFMA16(hn0, fC0, ap, 0, 0, 0);                                                     \
      ap = MFMA16(hn1, fC1, ap, 0, 0, 0);                                                     \
      if (l4 < 2) {                                                                           \
        _Pragma("unroll") for (int q = 0; q < 4; ++q)                                         \
            *(_Float16*)(smc + ((Y0W) << 2) + swz((l4 * 4 + q) * 128 + col2)) =               \
                (_Float16)leaky(ap[q]);                                                       \
      }                                                                                       \
      if ((T) >= 1) {                                                                         \
        const int asrc = (wid < 2) ? (Y0P) : L_Y0V;                                           \
        f32x4 ah = sp4(b1h);                                                                  \
        ah = MFMA16(lda(smc, asrc, 0, lane), fD0, ah, 0, 0, 0);                               \
        ah = MFMA16(lda(smc, asrc, 1, lane), fD1, ah, 0, 0, 0);                               \
        _Pragma("unroll") for (int q = 0; q < 4; ++q) {                                       \
          float tq = leaky(ah[q]) * wfh;                                                      \
          tq += __shfl_xor(tq, 1, 64);                                                        \
          tq += __shfl_xor(tq, 2, 64);                                                        \
          tq += __shfl_xor(tq, 4, 64);                                                        \
          tq += __shfl_xor(tq, 8, 64);                                                        \
          if (l15 == 0 && l4 < 2)                                                             \
            smf[L_PART + ((wid < 2) ? 0 : 16) + (wid & 1) * 8 + (l4 * 4 + q)] = tq;           \
        }                                                                                     \
      }                                                                                       \
    }                                                                                         \
    _Pragma("unroll") for (int q = 0; q < 4; ++q) {                                           \
      gprev[q] = gcur[q];                                                                     \
      gcur[q] = gnext[q];                                                                     \
    }                                                                                         \
    __syncthreads(); /* B2 */                                                                 \
  }

// ---- fused RNN: 8 rows/block, 256 blocks, 8 waves, weights in registers ----
extern "C" __global__ void __launch_bounds__(512, 1)
rnn_mfma(const float* __restrict__ x,
         const float* __restrict__ bxc, const float* __restrict__ bxv,
         const float* __restrict__ bpc0, const float* __restrict__ bpc1,
         const float* __restrict__ Wfcc, const float* __restrict__ bfcc,
         const float* __restrict__ bpv0, const float* __restrict__ bpv1,
         const float* __restrict__ Wfcv, const float* __restrict__ bfcv,
         const unsigned* __restrict__ ws, float* __restrict__ out) {
  extern __shared__ unsigned sm[];
  char* smc = (char*)sm;
  float* smf = (float*)sm;
  const int tid = threadIdx.x;
  const int lane = tid & 63, wid = tid >> 6;
  const int l15 = lane & 15, l4 = lane >> 4;
  const int wq = wid & 3;
  const bool cw = wid < 4;
  const int r0 = blockIdx.x * 8;

  // zero all LDS (tiles/part)
  for (int i = tid; i < L_TOT; i += 512) sm[i] = 0;

  // per-wave constants
  float bgate[4];
#pragma unroll
  for (int m = 0; m < 4; ++m) bgate[m] = (cw ? bxc : bxv)[(wq + 4 * m) * 16 + l15];
  const float b0u = (cw ? bpc0 : bpv0)[16 * wq + l15];
  const float b1h = (wid < 2 ? bpc1 : bpv1)[16 * (wid & 1) + l15];
  const float wfh = (wid < 2 ? Wfcc : Wfcv)[16 * (wid & 1) + l15];
  const float bfc = bfcc[0], bfv = bfcv[0];

  // hoisted B-fragments: gate weights fully in registers
  half8 wxF[8], whF[8];
#pragma unroll
  for (int m = 0; m < 4; ++m) {
    wxF[2 * m] = ldg8(ws, cw ? GOFF_WXC : GOFF_WXV, wq + 4 * m, 0, lane);
    wxF[2 * m + 1] = ldg8(ws, cw ? GOFF_WXC : GOFF_WXV, wq + 4 * m, 1, lane);
    whF[2 * m] = ldg8(ws, cw ? GOFF_WHC : GOFF_WHV, wq + 4 * m, 0, lane);
    whF[2 * m + 1] = ldg8(ws, cw ? GOFF_WHC : GOFF_WHV, wq + 4 * m, 1, lane);
  }
  half8 fA0, fA1, fB0, fB1, fC0, fC1, fD0, fD1;
  if (cw) {
    fA0 = ldg8(ws, GOFF_SCC, wq, 0, lane); fA1 = ldg8(ws, GOFF_SCC, wq, 1, lane);
    fB0 = ldg8(ws, GOFF_SCV, wq, 0, lane); fB1 = ldg8(ws, GOFF_SCV, wq, 1, lane);
    fC0 = ldg8(ws, GOFF_PC0, wq, 0, lane); fC1 = ldg8(ws, GOFF_PC0, wq, 1, lane);
    const int hoff = (wid < 2) ? GOFF_PC1 : GOFF_PV1;
    fD0 = ldg8(ws, hoff, wid & 1, 0, lane); fD1 = ldg8(ws, hoff, wid & 1, 1, lane);
  } else {
    fA0 = ldg8(ws, GOFF_SVV, wq, 0, lane); fA1 = ldg8(ws, GOFF_SVV, wq, 1, lane);
    fB0 = ldg8(ws, GOFF_SVC, wq, 0, lane); fB1 = ldg8(ws, GOFF_SVC, wq, 1, lane);
    fC0 = ldg8(ws, GOFF_PV0, wq, 0, lane); fC1 = ldg8(ws, GOFF_PV0, wq, 1, lane);
    fD0 = fA0; fD1 = fA1;  // unused by v-waves
  }

  // feat A-frag stream (compact; row = lane&7 via 2-way broadcast)
  const uint4* xfr = (const uint4*)(ws + WS_X) + (size_t)blockIdx.x * (TT * 64) +
                     (lane & 7) * 8 + (lane >> 4);
  half8 fx0, fx1, fy0, fy1;
  {
    union { uint4 u; half8 h; } u0_, u1_;
    u0_.u = xfr[0];
    u1_.u = xfr[4];
    fx0 = u0_.h;
    fx1 = u1_.h;
  }

  // clicks in registers: rows (l4&1)*4+q (valid for elem lanes l4<2)
  const float* xck = x + (size_t)(r0 + (l4 & 1) * 4) * ROWSTR + 64;
  float gprev[4] = {0.f, 0.f, 0.f, 0.f};  // click(t-1); g(-1)=0
  float gcur[4], gnext[4];
#pragma unroll
  for (int q = 0; q < 4; ++q) gcur[q] = xck[q * ROWSTR];  // click(0)

  float st[4] = {0.f, 0.f, 0.f, 0.f};     // s_c (c-waves) / s_v (v-waves)
  float hvold[4] = {0.f, 0.f, 0.f, 0.f};  // h_v regs (v-waves)
  float fvv[4], ivv[4], ovv[4], gvv[4], psv[4];
  const int col2 = (16 * wq + l15) * 2;
  float2* o2 = (float2*)out;

  __syncthreads();

  for (int t = 0; t < TT; t += 2) {
    STEP(t,     L_HC0, L_HC1, L_HV0, L_HV1, L_Y0C0, L_Y0C1, fx0, fx1, fy0, fy1)
    STEP(t + 1, L_HC1, L_HC0, L_HV1, L_HV0, L_Y0C1, L_Y0C0, fy0, fy1, fx0, fx1)
  }

  // ---- epilogue: out(198), out(199) ----
  if (wid == 7 && lane < 8) {
    float pc = sigm(smf[L_PART + lane] + smf[L_PART + 8 + lane] + bfc);
    float pv = sigm(smf[L_PART + 16 + lane] + smf[L_PART + 24 + lane] + bfv);
    o2[(size_t)(r0 + lane) * TT + (TT - 2)] = make_float2(pc, pv * pc);
  }
  if (!cw) {  // pv0(199): h_v(199) in L_HV0 (t=199 odd -> HVNEW = L_HV0)
    f32x4 apv = sp4(b0u);
    apv = MFMA16(lda(smc, L_HV0, 0, lane), fC0, apv, 0, 0, 0);
    apv = MFMA16(lda(smc, L_HV0, 1, lane), fC1, apv, 0, 0, 0);
    if (l4 < 2) {
#pragma unroll
      for (int q = 0; q < 4; ++q)
        *(_Float16*)(smc + (L_Y0V << 2) + swz((l4 * 4 + q) * 128 + col2)) =
            (_Float16)leaky(apv[q]);
    }
  }
  __syncthreads();
  if (cw) {  // heads(199): y0c(199) in L_Y0C1
    const int asrc = (wid < 2) ? L_Y0C1 : L_Y0V;
    f32x4 ah = sp4(b1h);
    ah = MFMA16(lda(smc, asrc, 0, lane), fD0, ah, 0, 0, 0);
    ah = MFMA16(lda(smc, asrc, 1, lane), fD1, ah, 0, 0, 0);
#pragma unroll
    for (int q = 0; q < 4; ++q) {
      float tq = leaky(ah[q]) * wfh;
      tq += __shfl_xor(tq, 1, 64);
      tq += __shfl_xor(tq, 2, 64);
      tq += __shfl_xor(tq, 4, 64);
      tq += __shfl_xor(tq, 8, 64);
      if (l15 == 0 && l4 < 2)
        smf[L_PART + ((wid < 2) ? 0 : 16) + (wid & 1) * 8 + (l4 * 4 + q)] = tq;
    }
  }
  __syncthreads();
  if (wid == 0 && lane < 8) {
    float pc = sigm(smf[L_PART + lane] + smf[L_PART + 8 + lane] + bfc);
    float pv = sigm(smf[L_PART + 16 + lane] + smf[L_PART + 24 + lane] + bfv);
    o2[(size_t)(r0 + lane) * TT + (TT - 1)] = make_float2(pc, pv * pc);
  }
}

extern "C" void kernel_launch(void* const* d_in, const int* in_sizes, int n_in,
                              void* d_out, int out_size, void* d_ws, size_t ws_size,
                              hipStream_t stream) {
  const float* x    = (const float*)d_in[0];
  const float* Wxc  = (const float*)d_in[1];
  const float* bxc  = (const float*)d_in[2];
  const float* Whc  = (const float*)d_in[3];
  const float* Wxv  = (const float*)d_in[4];
  const float* bxv  = (const float*)d_in[5];
  const float* Whv  = (const float*)d_in[6];
  const float* Wscc = (const float*)d_in[7];
  const float* Wscv = (const float*)d_in[8];
  const float* Wsvv = (const float*)d_in[9];
  const float* Wsvc = (const float*)d_in[10];
  const float* Wpc0 = (const float*)d_in[11];
  const float* bpc0 = (const float*)d_in[12];
  const float* Wpc1 = (const float*)d_in[13];
  const float* bpc1 = (const float*)d_in[14];
  const float* Wfcc = (const float*)d_in[15];
  const float* bfcc = (const float*)d_in[16];
  const float* Wpv0 = (const float*)d_in[17];
  const float* bpv0 = (const float*)d_in[18];
  const float* Wpv1 = (const float*)d_in[19];
  const float* bpv1 = (const float*)d_in[20];
  const float* Wfcv = (const float*)d_in[21];
  const float* bfcv = (const float*)d_in[22];
  float* out = (float*)d_out;
  unsigned* wsbuf = (unsigned*)d_ws;

  prepack<<<184, 256, 0, stream>>>(Wxc, Wxv, Whc, Whv, Wscc, Wscv, Wsvv, Wsvc,
                                   Wpc0, Wpv0, Wpc1, Wpv1, wsbuf);
  xpack<<<dim3(TT, 256), 256, 0, stream>>>(x, wsbuf + WS_X);

  (void)hipFuncSetAttribute(reinterpret_cast<const void*>(rnn_mfma),
                            hipFuncAttributeMaxDynamicSharedMemorySize, L_TOT * 4);
  rnn_mfma<<<256, 512, L_TOT * 4, stream>>>(
      x, bxc, bxv, bpc0, bpc1, Wfcc, bfcc, bpv0, bpv1, Wfcv, bfcv, wsbuf, out);
}

// Round 11
// 262.123 us; speedup vs baseline: 8.5463x; 1.4984x over previous
//
#include <hip/hip_runtime.h>

#define TT 200
#define XD 65
#define ROWSTR (TT * XD)  // 13000

typedef _Float16 h2 __attribute__((ext_vector_type(2)));
typedef _Float16 half8 __attribute__((ext_vector_type(8)));
typedef float f32x4 __attribute__((ext_vector_type(4)));

#define MFMA16 __builtin_amdgcn_mfma_f32_16x16x32_f16

// ---- ws dword offsets: prepacked f16 B-fragment pools + feat A-frag stream ----
#define GOFF_WXC 0
#define GOFF_WXV 8192
#define GOFF_WHC 16384
#define GOFF_WHV 24576
#define GOFF_SCC 32768
#define GOFF_SCV 34816
#define GOFF_SVV 36864
#define GOFF_SVC 38912
#define GOFF_PC0 40960
#define GOFF_PV0 43008
#define GOFF_PC1 45056
#define GOFF_PV1 46080
#define GTOT     47104
#define WS_X     47104ull  // feats: 256 b * 200 t * 256 dw (compact f16 pairs)

// ---- LDS dword offsets (tiles only) ----
#define L_HC0 0      // 512-dw tiles: [16 rows][64 f16] swizzled; rows {2,3,6,7,...} stay 0
#define L_HC1 512
#define L_HV0 1024
#define L_HV1 1536
#define L_Y0C0 2048
#define L_Y0C1 2560
#define L_Y0V  3072
#define L_PART 3584  // 32 floats
#define L_TOT  3616  // 14,464 B

__device__ __forceinline__ unsigned pk(float lo, float hi) {
  union { h2 h; unsigned u; } c;
  c.h.x = (_Float16)lo;
  c.h.y = (_Float16)hi;
  return c.u;
}

__device__ __forceinline__ float fexp2(float x) {
#if __has_builtin(__builtin_amdgcn_exp2f)
  return __builtin_amdgcn_exp2f(x);
#else
  return __expf(x * 0.6931471805599453f);
#endif
}
__device__ __forceinline__ float frcp(float x) {
#if __has_builtin(__builtin_amdgcn_rcpf)
  return __builtin_amdgcn_rcpf(x);
#else
  return 1.0f / x;
#endif
}
__device__ __forceinline__ float sigm(float x) { return frcp(1.f + fexp2(x * -1.44269504f)); }
__device__ __forceinline__ float tanh_fast(float x) {
  return fmaf(2.f, frcp(1.f + fexp2(x * -2.88539008f)), -1.f);
}
__device__ __forceinline__ float leaky(float x) { return x > 0.0f ? x : 0.3f * x; }
__device__ __forceinline__ f32x4 sp4(float v) { f32x4 r = {v, v, v, v}; return r; }

// XOR swizzle within a [16][128B] tile
__device__ __forceinline__ int swz(int b) { return b ^ ((b >> 3) & 0x70); }

// A-frag: row = lane&15, k = kh*32 + 8*(lane>>4) + i
__device__ __forceinline__ half8 lda(const char* smc, int dwoff, int kh, int lane) {
  int byte = (lane & 15) * 128 + kh * 64 + ((lane >> 4) << 4);
  union { uint4 u; half8 h; } c;
  c.u = *(const uint4*)(smc + (dwoff << 2) + swz(byte));
  return c.h;
}
// B-frag from global ws pool
__device__ __forceinline__ half8 ldg8(const unsigned* ws, int off, int n, int kh, int lane) {
  union { uint4 u; half8 h; } c;
  c.u = *(const uint4*)(ws + off + (((n * 2 + kh) * 64 + lane) << 2));
  return c.h;
}

// ---- prepack: f32 weights -> f16 B-fragment pools in ws (verified) ----
extern "C" __global__ void prepack(const float* __restrict__ Wxc, const float* __restrict__ Wxv,
                                   const float* __restrict__ Whc, const float* __restrict__ Whv,
                                   const float* __restrict__ Wscc, const float* __restrict__ Wscv,
                                   const float* __restrict__ Wsvv, const float* __restrict__ Wsvc,
                                   const float* __restrict__ Wpc0, const float* __restrict__ Wpv0,
                                   const float* __restrict__ Wpc1, const float* __restrict__ Wpv1,
                                   unsigned* __restrict__ wsout) {
  int idx = blockIdx.x * 256 + threadIdx.x;
  if (idx >= GTOT) return;
  const float* W; int base, ncol;
  if      (idx < GOFF_WXV) { W = Wxc;  base = GOFF_WXC; ncol = 256; }
  else if (idx < GOFF_WHC) { W = Wxv;  base = GOFF_WXV; ncol = 256; }
  else if (idx < GOFF_WHV) { W = Whc;  base = GOFF_WHC; ncol = 256; }
  else if (idx < GOFF_SCC) { W = Whv;  base = GOFF_WHV; ncol = 256; }
  else if (idx < GOFF_SCV) { W = Wscc; base = GOFF_SCC; ncol = 64; }
  else if (idx < GOFF_SVV) { W = Wscv; base = GOFF_SCV; ncol = 64; }
  else if (idx < GOFF_SVC) { W = Wsvv; base = GOFF_SVV; ncol = 64; }
  else if (idx < GOFF_PC0) { W = Wsvc; base = GOFF_SVC; ncol = 64; }
  else if (idx < GOFF_PV0) { W = Wpc0; base = GOFF_PC0; ncol = 64; }
  else if (idx < GOFF_PC1) { W = Wpv0; base = GOFF_PV0; ncol = 64; }
  else if (idx < GOFF_PV1) { W = Wpc1; base = GOFF_PC1; ncol = 32; }
  else                     { W = Wpv1; base = GOFF_PV1; ncol = 32; }
  int local = idx - base;
  int d = local & 3, lane = (local >> 2) & 63, nk = local >> 8;
  int kh = nk & 1, n = nk >> 1;
  int k0 = kh * 32 + ((lane >> 4) << 3) + (d << 1);
  int c = n * 16 + (lane & 15);
  wsout[idx] = pk(W[k0 * ncol + c], W[(k0 + 1) * ncol + c]);
}

// ---- xpack: feats -> compact f16 pair stream [b][t][row8][32dw] (unchanged) ----
extern "C" __global__ void xpack(const float* __restrict__ x, unsigned* __restrict__ wsx) {
  int t = blockIdx.x;   // 200
  int b = blockIdx.y;   // 256
  int tid = threadIdx.x;  // 256
  int row8 = tid >> 5, kdw = tid & 31;
  const float* p = x + (size_t)(b * 8 + row8) * ROWSTR + t * XD + kdw * 2;
  wsx[((size_t)b * TT + t) * 256 + tid] = pk(p[0], p[1]);
}

// One RNN step; parity constants compile-time via 2x-unrolled caller.
// Batch row br = l4*2+q (q in {0,1}) lives at C/tile row l4*4+q.
#define STEP(T, HCUR, HNEW, HVCUR, HVNEW, Y0W, Y0P, FC0, FC1, FN0, FN1)                       \
  {                                                                                           \
    if ((T) >= 2 && wid == 7 && lane < 8) {                                                   \
      float pc = sigm(smf[L_PART + lane] + smf[L_PART + 8 + lane] + bfc);                     \
      float pv = sigm(smf[L_PART + 16 + lane] + smf[L_PART + 24 + lane] + bfv);               \
      o2[(size_t)(r0 + lane) * TT + ((T) - 2)] = make_float2(pc, pv * pc);                    \
    }                                                                                         \
    half8 hv0 = lda(smc, HVCUR, 0, lane), hv1 = lda(smc, HVCUR, 1, lane);                     \
    if (cw) {                                                                                 \
      half8 hc0 = lda(smc, HCUR, 0, lane), hc1 = lda(smc, HCUR, 1, lane);                     \
      f32x4 a0_ = sp4(bgate[0]), a1_ = sp4(bgate[1]), a2_ = sp4(bgate[2]),                    \
            a3_ = sp4(bgate[3]);                                                              \
      __builtin_amdgcn_s_setprio(1);                                                          \
      a0_ = MFMA16(FC0, wxF[0], a0_, 0, 0, 0);                                                \
      a0_ = MFMA16(FC1, wxF[1], a0_, 0, 0, 0);                                                \
      a0_ = MFMA16(hc0, whF[0], a0_, 0, 0, 0);                                                \
      a0_ = MFMA16(hc1, whF[1], a0_, 0, 0, 0);                                                \
      a1_ = MFMA16(FC0, wxF[2], a1_, 0, 0, 0);                                                \
      a1_ = MFMA16(FC1, wxF[3], a1_, 0, 0, 0);                                                \
      a1_ = MFMA16(hc0, whF[2], a1_, 0, 0, 0);                                                \
      a1_ = MFMA16(hc1, whF[3], a1_, 0, 0, 0);                                                \
      a2_ = MFMA16(FC0, wxF[4], a2_, 0, 0, 0);                                                \
      a2_ = MFMA16(FC1, wxF[5], a2_, 0, 0, 0);                                                \
      a2_ = MFMA16(hc0, whF[4], a2_, 0, 0, 0);                                                \
      a2_ = MFMA16(hc1, whF[5], a2_, 0, 0, 0);                                                \
      a3_ = MFMA16(FC0, wxF[6], a3_, 0, 0, 0);                                                \
      a3_ = MFMA16(FC1, wxF[7], a3_, 0, 0, 0);                                                \
      a3_ = MFMA16(hc0, whF[6], a3_, 0, 0, 0);                                                \
      a3_ = MFMA16(hc1, whF[7], a3_, 0, 0, 0);                                                \
      f32x4 pscc = sp4(0.f), pscv = sp4(0.f);                                                 \
      pscc = MFMA16(hc0, fA0, pscc, 0, 0, 0);                                                 \
      pscc = MFMA16(hc1, fA1, pscc, 0, 0, 0);                                                 \
      pscv = MFMA16(hv0, fB0, pscv, 0, 0, 0);                                                 \
      pscv = MFMA16(hv1, fB1, pscv, 0, 0, 0);                                                 \
      __builtin_amdgcn_s_setprio(0);                                                          \
      _Pragma("unroll") for (int q = 0; q < 2; ++q) {                                         \
        bool gp = gprev[q] >= 0.5f;                                                           \
        float f = sigm(a0_[q]), ii = sigm(a1_[q]), o = sigm(a2_[q]);                          \
        float gc = tanh_fast(a3_[q]);                                                         \
        float sh = tanh_fast(gp ? pscv[q] : pscc[q]);                                         \
        float s = sh + ii * gc + (gp ? 0.f : f * st[q]);                                      \
        st[q] = s;                                                                            \
        float hcn = o * tanh_fast(s);                                                         \
        *(_Float16*)(smc + ((HNEW) << 2) + swz((l4 * 4 + q) * 128 + col2)) = (_Float16)hcn;   \
      }                                                                                       \
    } else {                                                                                  \
      f32x4 a0_ = sp4(bgate[0]), a1_ = sp4(bgate[1]), a2_ = sp4(bgate[2]),                    \
            a3_ = sp4(bgate[3]);                                                              \
      __builtin_amdgcn_s_setprio(1);                                                          \
      a0_ = MFMA16(FC0, wxF[0], a0_, 0, 0, 0);                                                \
      a0_ = MFMA16(FC1, wxF[1], a0_, 0, 0, 0);                                                \
      a0_ = MFMA16(hv0, whF[0], a0_, 0, 0, 0);                                                \
      a0_ = MFMA16(hv1, whF[1], a0_, 0, 0, 0);                                                \
      a1_ = MFMA16(FC0, wxF[2], a1_, 0, 0, 0);                                                \
      a1_ = MFMA16(FC1, wxF[3], a1_, 0, 0, 0);                                                \
      a1_ = MFMA16(hv0, whF[2], a1_, 0, 0, 0);                                                \
      a1_ = MFMA16(hv1, whF[3], a1_, 0, 0, 0);                                                \
      a2_ = MFMA16(FC0, wxF[4], a2_, 0, 0, 0);                                                \
      a2_ = MFMA16(FC1, wxF[5], a2_, 0, 0, 0);                                                \
      a2_ = MFMA16(hv0, whF[4], a2_, 0, 0, 0);                                                \
      a2_ = MFMA16(hv1, whF[5], a2_, 0, 0, 0);                                                \
      a3_ = MFMA16(FC0, wxF[6], a3_, 0, 0, 0);                                                \
      a3_ = MFMA16(FC1, wxF[7], a3_, 0, 0, 0);                                                \
      a3_ = MFMA16(hv0, whF[6], a3_, 0, 0, 0);                                                \
      a3_ = MFMA16(hv1, whF[7], a3_, 0, 0, 0);                                                \
      f32x4 psvv = sp4(0.f);                                                                  \
      psvv = MFMA16(hv0, fA0, psvv, 0, 0, 0);                                                 \
      psvv = MFMA16(hv1, fA1, psvv, 0, 0, 0);                                                 \
      __builtin_amdgcn_s_setprio(0);                                                          \
      if ((T) >= 1) {                                                                         \
        f32x4 apv = sp4(b0u);                                                                 \
        apv = MFMA16(hv0, fC0, apv, 0, 0, 0);                                                 \
        apv = MFMA16(hv1, fC1, apv, 0, 0, 0);                                                 \
        _Pragma("unroll") for (int q = 0; q < 2; ++q)                                         \
            *(_Float16*)(smc + (L_Y0V << 2) + swz((l4 * 4 + q) * 128 + col2)) =               \
                (_Float16)leaky(apv[q]);                                                      \
      }                                                                                       \
      _Pragma("unroll") for (int q = 0; q < 2; ++q) {                                         \
        fvv[q] = sigm(a0_[q]);                                                                \
        ivv[q] = sigm(a1_[q]);                                                                \
        ovv[q] = sigm(a2_[q]);                                                                \
        gvv[q] = tanh_fast(a3_[q]);                                                           \
        psv[q] = psvv[q];                                                                     \
      }                                                                                       \
    }                                                                                         \
    {                                                                                         \
      const int tn_ = ((T) + 1 < TT) ? (T) + 1 : (TT - 1);                                    \
      union { uint4 u; half8 h; } u0_, u1_;                                                   \
      u0_.u = xfr[tn_ * 64];                                                                  \
      u1_.u = xfr[tn_ * 64 + 4];                                                              \
      FN0 = u0_.h;                                                                            \
      FN1 = u1_.h;                                                                            \
      gnext[0] = xck[tn_ * XD];                                                               \
      gnext[1] = xck[ROWSTR + tn_ * XD];                                                      \
    }                                                                                         \
    __syncthreads(); /* B1 */                                                                 \
    half8 hn0 = lda(smc, HNEW, 0, lane), hn1 = lda(smc, HNEW, 1, lane);                       \
    if (!cw) {                                                                                \
      f32x4 psvc = sp4(0.f);                                                                  \
      psvc = MFMA16(hn0, fB0, psvc, 0, 0, 0);                                                 \
      psvc = MFMA16(hn1, fB1, psvc, 0, 0, 0);                                                 \
      _Pragma("unroll") for (int q = 0; q < 2; ++q) {                                         \
        bool g = gcur[q] >= 0.5f;                                                             \
        float sh = tanh_fast(g ? psv[q] + psvc[q] : psv[q]);                                  \
        float s = sh + (g ? fvv[q] * st[q] + ivv[q] * gvv[q] : st[q]);                        \
        st[q] = s;                                                                            \
        float hvn = g ? ovv[q] * tanh_fast(s) : hvold[q];                                     \
        hvold[q] = hvn;                                                                       \
        *(_Float16*)(smc + ((HVNEW) << 2) + swz((l4 * 4 + q) * 128 + col2)) = (_Float16)hvn;  \
      }                                                                                       \
    } else {                                                                                  \
      f32x4 ap = sp4(b0u);                                                                    \
      ap = MFMA16(hn0, fC0, ap, 0, 0, 0);                                                     \
      ap = MFMA16(hn1, fC1, ap, 0, 0, 0);                                                     \
      _Pragma("unroll") for (int q = 0; q < 2; ++q)                                           \
          *(_Float16*)(smc + ((Y0W) << 2) + swz((l4 * 4 + q) * 128 + col2)) =                 \
              (_Float16)leaky(ap[q]);                                                         \
      if ((T) >= 1) {                                                                         \
        const int asrc = (wid < 2) ? (Y0P) : L_Y0V;                                           \
        f32x4 ah = sp4(b1h);                                                                  \
        ah = MFMA16(lda(smc, asrc, 0, lane), fD0, ah, 0, 0, 0);                               \
        ah = MFMA16(lda(smc, asrc, 1, lane), fD1, ah, 0, 0, 0);                               \
        _Pragma("unroll") for (int q = 0; q < 2; ++q) {                                       \
          float tq = leaky(ah[q]) * wfh;                                                      \
          tq += __shfl_xor(tq, 1, 64);                                                        \
          tq += __shfl_xor(tq, 2, 64);                                                        \
          tq += __shfl_xor(tq, 4, 64);                                                        \
          tq += __shfl_xor(tq, 8, 64);                                                        \
          if (l15 == 0)                                                                       \
            smf[L_PART + ((wid < 2) ? 0 : 16) + (wid & 1) * 8 + (l4 * 2 + q)] = tq;           \
        }                                                                                     \
      }                                                                                       \
    }                                                                                         \
    _Pragma("unroll") for (int q = 0; q < 2; ++q) {                                           \
      gprev[q] = gcur[q];                                                                     \
      gcur[q] = gnext[q];                                                                     \
    }                                                                                         \
    __syncthreads(); /* B2 */                                                                 \
  }

// ---- fused RNN: 8 rows/block, 256 blocks, 8 waves, rows at C-slots q<2 ----
extern "C" __global__ void __launch_bounds__(512, 1)
rnn_mfma(const float* __restrict__ x,
         const float* __restrict__ bxc, const float* __restrict__ bxv,
         const float* __restrict__ bpc0, const float* __restrict__ bpc1,
         const float* __restrict__ Wfcc, const float* __restrict__ bfcc,
         const float* __restrict__ bpv0, const float* __restrict__ bpv1,
         const float* __restrict__ Wfcv, const float* __restrict__ bfcv,
         const unsigned* __restrict__ ws, float* __restrict__ out) {
  extern __shared__ unsigned sm[];
  char* smc = (char*)sm;
  float* smf = (float*)sm;
  const int tid = threadIdx.x;
  const int lane = tid & 63, wid = tid >> 6;
  const int l15 = lane & 15, l4 = lane >> 4;
  const int wq = wid & 3;
  const bool cw = wid < 4;
  const int r0 = blockIdx.x * 8;

  // zero all LDS (tiles/part)
  for (int i = tid; i < L_TOT; i += 512) sm[i] = 0;

  // per-wave constants
  float bgate[4];
#pragma unroll
  for (int m = 0; m < 4; ++m) bgate[m] = (cw ? bxc : bxv)[(wq + 4 * m) * 16 + l15];
  const float b0u = (cw ? bpc0 : bpv0)[16 * wq + l15];
  const float b1h = (wid < 2 ? bpc1 : bpv1)[16 * (wid & 1) + l15];
  const float wfh = (wid < 2 ? Wfcc : Wfcv)[16 * (wid & 1) + l15];
  const float bfc = bfcc[0], bfv = bfcv[0];

  // hoisted B-fragments: gate weights fully in registers
  half8 wxF[8], whF[8];
#pragma unroll
  for (int m = 0; m < 4; ++m) {
    wxF[2 * m] = ldg8(ws, cw ? GOFF_WXC : GOFF_WXV, wq + 4 * m, 0, lane);
    wxF[2 * m + 1] = ldg8(ws, cw ? GOFF_WXC : GOFF_WXV, wq + 4 * m, 1, lane);
    whF[2 * m] = ldg8(ws, cw ? GOFF_WHC : GOFF_WHV, wq + 4 * m, 0, lane);
    whF[2 * m + 1] = ldg8(ws, cw ? GOFF_WHC : GOFF_WHV, wq + 4 * m, 1, lane);
  }
  half8 fA0, fA1, fB0, fB1, fC0, fC1, fD0, fD1;
  if (cw) {
    fA0 = ldg8(ws, GOFF_SCC, wq, 0, lane); fA1 = ldg8(ws, GOFF_SCC, wq, 1, lane);
    fB0 = ldg8(ws, GOFF_SCV, wq, 0, lane); fB1 = ldg8(ws, GOFF_SCV, wq, 1, lane);
    fC0 = ldg8(ws, GOFF_PC0, wq, 0, lane); fC1 = ldg8(ws, GOFF_PC0, wq, 1, lane);
    const int hoff = (wid < 2) ? GOFF_PC1 : GOFF_PV1;
    fD0 = ldg8(ws, hoff, wid & 1, 0, lane); fD1 = ldg8(ws, hoff, wid & 1, 1, lane);
  } else {
    fA0 = ldg8(ws, GOFF_SVV, wq, 0, lane); fA1 = ldg8(ws, GOFF_SVV, wq, 1, lane);
    fB0 = ldg8(ws, GOFF_SVC, wq, 0, lane); fB1 = ldg8(ws, GOFF_SVC, wq, 1, lane);
    fC0 = ldg8(ws, GOFF_PV0, wq, 0, lane); fC1 = ldg8(ws, GOFF_PV0, wq, 1, lane);
    fD0 = fA0; fD1 = fA1;  // unused by v-waves
  }

  // feat A-frag stream: tile row l15 -> batch row br = ((l15>>1)&6)|(l15&1)
  const int brx = ((l15 >> 1) & 6) | (l15 & 1);
  const uint4* xfr = (const uint4*)(ws + WS_X) + (size_t)blockIdx.x * (TT * 64) +
                     brx * 8 + l4;
  half8 fx0, fx1, fy0, fy1;
  {
    union { uint4 u; half8 h; } u0_, u1_;
    u0_.u = xfr[0];
    u1_.u = xfr[4];
    fx0 = u0_.h;
    fx1 = u1_.h;
  }

  // clicks in registers: lane handles rows l4*2 + q (q in {0,1})
  const float* xck = x + (size_t)(r0 + l4 * 2) * ROWSTR + 64;
  float gprev[2] = {0.f, 0.f};  // click(t-1); g(-1)=0
  float gcur[2], gnext[2];
  gcur[0] = xck[0];
  gcur[1] = xck[ROWSTR];

  float st[2] = {0.f, 0.f};     // s_c (c-waves) / s_v (v-waves)
  float hvold[2] = {0.f, 0.f};  // h_v regs (v-waves)
  float fvv[2], ivv[2], ovv[2], gvv[2], psv[2];
  const int col2 = (16 * wq + l15) * 2;
  float2* o2 = (float2*)out;

  __syncthreads();

  for (int t = 0; t < TT; t += 2) {
    STEP(t,     L_HC0, L_HC1, L_HV0, L_HV1, L_Y0C0, L_Y0C1, fx0, fx1, fy0, fy1)
    STEP(t + 1, L_HC1, L_HC0, L_HV1, L_HV0, L_Y0C1, L_Y0C0, fy0, fy1, fx0, fx1)
  }

  // ---- epilogue: out(198), out(199) ----
  if (wid == 7 && lane < 8) {
    float pc = sigm(smf[L_PART + lane] + smf[L_PART + 8 + lane] + bfc);
    float pv = sigm(smf[L_PART + 16 + lane] + smf[L_PART + 24 + lane] + bfv);
    o2[(size_t)(r0 + lane) * TT + (TT - 2)] = make_float2(pc, pv * pc);
  }
  if (!cw) {  // pv0(199): h_v(199) in L_HV0 (t=199 odd -> HVNEW = L_HV0)
    f32x4 apv = sp4(b0u);
    apv = MFMA16(lda(smc, L_HV0, 0, lane), fC0, apv, 0, 0, 0);
    apv = MFMA16(lda(smc, L_HV0, 1, lane), fC1, apv, 0, 0, 0);
#pragma unroll
    for (int q = 0; q < 2; ++q)
      *(_Float16*)(smc + (L_Y0V << 2) + swz((l4 * 4 + q) * 128 + col2)) =
          (_Float16)leaky(apv[q]);
  }
  __syncthreads();
  if (cw) {  // heads(199): y0c(199) in L_Y0C1
    const int asrc = (wid < 2) ? L_Y0C1 : L_Y0V;
    f32x4 ah = sp4(b1h);
    ah = MFMA16(lda(smc, asrc, 0, lane), fD0, ah, 0, 0, 0);
    ah = MFMA16(lda(smc, asrc, 1, lane), fD1, ah, 0, 0, 0);
#pragma unroll
    for (int q = 0; q < 2; ++q) {
      float tq = leaky(ah[q]) * wfh;
      tq += __shfl_xor(tq, 1, 64);
      tq += __shfl_xor(tq, 2, 64);
      tq += __shfl_xor(tq, 4, 64);
      tq += __shfl_xor(tq, 8, 64);
      if (l15 == 0)
        smf[L_PART + ((wid < 2) ? 0 : 16) + (wid & 1) * 8 + (l4 * 2 + q)] = tq;
    }
  }
  __syncthreads();
  if (wid == 0 && lane < 8) {
    float pc = sigm(smf[L_PART + lane] + smf[L_PART + 8 + lane] + bfc);
    float pv = sigm(smf[L_PART + 16 + lane] + smf[L_PART + 24 + lane] + bfv);
    o2[(size_t)(r0 + lane) * TT + (TT - 1)] = make_float2(pc, pv * pc);
  }
}

extern "C" void kernel_launch(void* const* d_in, const int* in_sizes, int n_in,
                              void* d_out, int out_size, void* d_ws, size_t ws_size,
                              hipStream_t stream) {
  const float* x    = (const float*)d_in[0];
  const float* Wxc  = (const float*)d_in[1];
  const float* bxc  = (const float*)d_in[2];
  const float* Whc  = (const float*)d_in[3];
  const float* Wxv  = (const float*)d_in[4];
  const float* bxv  = (const float*)d_in[5];
  const float* Whv  = (const float*)d_in[6];
  const float* Wscc = (const float*)d_in[7];
  const float* Wscv = (const float*)d_in[8];
  const float* Wsvv = (const float*)d_in[9];
  const float* Wsvc = (const float*)d_in[10];
  const float* Wpc0 = (const float*)d_in[11];
  const float* bpc0 = (const float*)d_in[12];
  const float* Wpc1 = (const float*)d_in[13];
  const float* bpc1 = (const float*)d_in[14];
  const float* Wfcc = (const float*)d_in[15];
  const float* bfcc = (const float*)d_in[16];
  const float* Wpv0 = (const float*)d_in[17];
  const float* bpv0 = (const float*)d_in[18];
  const float* Wpv1 = (const float*)d_in[19];
  const float* bpv1 = (const float*)d_in[20];
  const float* Wfcv = (const float*)d_in[21];
  const float* bfcv = (const float*)d_in[22];
  float* out = (float*)d_out;
  unsigned* wsbuf = (unsigned*)d_ws;

  prepack<<<184, 256, 0, stream>>>(Wxc, Wxv, Whc, Whv, Wscc, Wscv, Wsvv, Wsvc,
                                   Wpc0, Wpv0, Wpc1, Wpv1, wsbuf);
  xpack<<<dim3(TT, 256), 256, 0, stream>>>(x, wsbuf + WS_X);

  (void)hipFuncSetAttribute(reinterpret_cast<const void*>(rnn_mfma),
                            hipFuncAttributeMaxDynamicSharedMemorySize, L_TOT * 4);
  rnn_mfma<<<256, 512, L_TOT * 4, stream>>>(
      x, bxc, bxv, bpc0, bpc1, Wfcc, bfcc, bpv0, bpv1, Wfcv, bfcv, wsbuf, out);
}